// Round 7
// baseline (427.271 us; speedup 1.0000x reference)
//
#include <hip/hip_runtime.h>

constexpr int DD = 128;

typedef __attribute__((ext_vector_type(8))) short short8_t;            // 8 bf16 = 4 VGPR
typedef __attribute__((ext_vector_type(8))) unsigned short ushort8_t;  // 16 B
typedef __attribute__((ext_vector_type(4))) float f32x4;

__device__ __forceinline__ float bf2f(unsigned short u) {
  union { unsigned int i; float f; } c;
  c.i = ((unsigned int)u) << 16;
  return c.f;
}
__device__ __forceinline__ unsigned short f2bf(float f) {
  union { float f; unsigned int i; } c;
  c.f = f;
  unsigned int x = c.i;
  x += 0x7fff + ((x >> 16) & 1);  // RNE
  return (unsigned short)(x >> 16);
}

// ================= counts (lean: no LDS, low VGPR, full occupancy) =================
__global__ void __launch_bounds__(256) counts_k(
    const int* __restrict__ esrc, const int* __restrict__ etgt, int E,
    const int* __restrict__ a2f, int N, const int* __restrict__ ftgt, int FE,
    int* __restrict__ cnt_src, int* __restrict__ cnt_tgt,
    int* __restrict__ cnt_a2f, int* __restrict__ cnt_fe,
    int* __restrict__ rank_tgt, int* __restrict__ rank_a2f, int* __restrict__ rank_fe) {
  int i = blockIdx.x * 256 + threadIdx.x;
  if (i < E) {
    atomicAdd(&cnt_src[esrc[i]], 1);
    rank_tgt[i] = atomicAdd(&cnt_tgt[etgt[i]], 1);
  } else if (i < E + N) {
    int j = i - E;
    rank_a2f[j] = atomicAdd(&cnt_a2f[a2f[j]], 1);
  } else if (i < E + N + FE) {
    int e = i - E - N;
    rank_fe[e] = atomicAdd(&cnt_fe[ftgt[e]], 1);
  }
}

// ====== MFMA GEMM: h' = bf16((x @ W + b) * dinv[row])  (scale free in epilogue) ======
__global__ void __launch_bounds__(256) mfma_h_k(
    const float* __restrict__ x, const float* __restrict__ W,
    const float* __restrict__ bias, const float* __restrict__ dinv,
    unsigned short* __restrict__ hout, int nrows) {
  __shared__ unsigned int wt[8192];  // 128 cols x 64 dwords, swizzled

  const int tid = threadIdx.x;
  const int rbase = blockIdx.x * 128;

  {  // stage Wt[c][k] = bf16(W[k][c]), dword-packed (k even|odd), swizzled
    int c = tid & 127;
    int half = tid >> 7;
#pragma unroll 4
    for (int j = 0; j < 32; j++) {
      int p = j * 2 + half;  // dword index = k/2
      int k = p * 2;
      float w0 = W[k * 128 + c];
      float w1 = W[(k + 1) * 128 + c];
      unsigned int packed = (unsigned int)f2bf(w0) | ((unsigned int)f2bf(w1) << 16);
      wt[(64 * c + p) ^ ((c & 7) << 2)] = packed;
    }
  }

  const int wave = tid >> 6;
  const int lane = tid & 63;
  const int l15 = lane & 15;
  const int kg = lane >> 4;

  float bcol[8];
#pragma unroll
  for (int ct = 0; ct < 8; ct++) bcol[ct] = bias[ct * 16 + l15];
  float dv[8];
#pragma unroll
  for (int rt = 0; rt < 2; rt++)
#pragma unroll
    for (int i = 0; i < 4; i++) {
      int gr = rbase + wave * 32 + rt * 16 + kg * 4 + i;
      dv[rt * 4 + i] = (gr < nrows) ? dinv[gr] : 0.f;
    }

  __syncthreads();

  f32x4 acc[2][8];
#pragma unroll
  for (int rt = 0; rt < 2; rt++)
#pragma unroll
    for (int ct = 0; ct < 8; ct++) acc[rt][ct] = (f32x4)(0.f);

#pragma unroll
  for (int ks = 0; ks < 4; ks++) {
    int kcol = ks * 32 + kg * 8;
    short8_t a[2];
#pragma unroll
    for (int rt = 0; rt < 2; rt++) {
      int row = rbase + wave * 32 + rt * 16 + l15;
      if (row < nrows) {
        const float4* xr = reinterpret_cast<const float4*>(x + (size_t)row * 128 + kcol);
        float4 v0 = xr[0], v1 = xr[1];
        a[rt][0] = (short)f2bf(v0.x); a[rt][1] = (short)f2bf(v0.y);
        a[rt][2] = (short)f2bf(v0.z); a[rt][3] = (short)f2bf(v0.w);
        a[rt][4] = (short)f2bf(v1.x); a[rt][5] = (short)f2bf(v1.y);
        a[rt][6] = (short)f2bf(v1.z); a[rt][7] = (short)f2bf(v1.w);
      } else {
#pragma unroll
        for (int e = 0; e < 8; e++) a[rt][e] = 0;
      }
    }
#pragma unroll
    for (int ct = 0; ct < 8; ct++) {
      int col = ct * 16 + l15;
      int dw0 = (64 * col + ks * 16 + kg * 4) ^ ((col & 7) << 2);
      short8_t b = *reinterpret_cast<const short8_t*>(&wt[dw0]);
      acc[0][ct] = __builtin_amdgcn_mfma_f32_16x16x32_bf16(a[0], b, acc[0][ct], 0, 0, 0);
      acc[1][ct] = __builtin_amdgcn_mfma_f32_16x16x32_bf16(a[1], b, acc[1][ct], 0, 0, 0);
    }
  }

#pragma unroll
  for (int rt = 0; rt < 2; rt++)
#pragma unroll
    for (int ct = 0; ct < 8; ct++)
#pragma unroll
      for (int i = 0; i < 4; i++) {
        int gr = rbase + wave * 32 + rt * 16 + kg * 4 + i;
        if (gr < nrows)
          hout[(size_t)gr * 128 + ct * 16 + l15] =
              f2bf((acc[rt][ct][i] + bcol[ct]) * dv[rt * 4 + i]);
      }
}

// ===== scanA: blocks [0,nb): block sums of cnt_tgt; block nb: a2f scan; nb+1: fe scan =====
__global__ void __launch_bounds__(256) scanA_k(
    const int* __restrict__ cnt_tgt, int n, int nb, int* __restrict__ bsums,
    const int* __restrict__ cnt_a2f, int* __restrict__ off_a2f,
    const int* __restrict__ cnt_fe, int* __restrict__ off_fe, int nf) {
  __shared__ int s[256];
  int t = threadIdx.x;
  int bid = blockIdx.x;
  if (bid < nb) {
    int base = bid * 1024;
    int v = 0;
    for (int i = t; i < 1024; i += 256) {
      int g = base + i;
      if (g < n) v += cnt_tgt[g];
    }
    s[t] = v;
    __syncthreads();
    for (int d = 128; d > 0; d >>= 1) {
      if (t < d) s[t] += s[t + d];
      __syncthreads();
    }
    if (t == 0) bsums[bid] = s[0];
  } else {
    const int* in = (bid == nb) ? cnt_a2f : cnt_fe;
    int* off = (bid == nb) ? off_a2f : off_fe;
    int carry = 0;
    for (int base = 0; base < nf; base += 256) {
      int v = (base + t < nf) ? in[base + t] : 0;
      __syncthreads();
      s[t] = v;
      __syncthreads();
      for (int d = 1; d < 256; d <<= 1) {
        int u = (t >= d) ? s[t - d] : 0;
        __syncthreads();
        s[t] += u;
        __syncthreads();
      }
      if (base + t < nf) off[base + t] = s[t] - v + carry;
      carry += s[255];
    }
  }
}

// ===== scanB: exclusive scan cnt_tgt -> off_tgt (prefix from bsums inline) + dinv =====
__global__ void __launch_bounds__(256) scanB_k(
    const int* __restrict__ in, int n, const int* __restrict__ bsums,
    int* __restrict__ off, const int* __restrict__ cnt_src,
    float* __restrict__ dinv) {
  __shared__ int s[256];
  int t = threadIdx.x;
  int bid = blockIdx.x;
  s[t] = (t < bid) ? bsums[t] : 0;  // nb <= 256
  __syncthreads();
  for (int d = 128; d > 0; d >>= 1) {
    if (t < d) s[t] += s[t + d];
    __syncthreads();
  }
  int prefix = s[0];
  __syncthreads();

  int base = bid * 1024 + t * 4;
  int a0 = (base + 0 < n) ? in[base + 0] : 0;
  int a1 = (base + 1 < n) ? in[base + 1] : 0;
  int a2 = (base + 2 < n) ? in[base + 2] : 0;
  int a3 = (base + 3 < n) ? in[base + 3] : 0;
  int tot = a0 + a1 + a2 + a3;
  s[t] = tot;
  __syncthreads();
  for (int d = 1; d < 256; d <<= 1) {
    int u = (t >= d) ? s[t - d] : 0;
    __syncthreads();
    s[t] += u;
    __syncthreads();
  }
  int pre = s[t] - tot + prefix;
  int e0 = pre, e1 = pre + a0, e2 = e1 + a1, e3 = e2 + a2;
  if (base + 0 < n) { off[base + 0] = e0; dinv[base + 0] = rsqrtf((float)(cnt_src[base + 0] + 1)); }
  if (base + 1 < n) { off[base + 1] = e1; dinv[base + 1] = rsqrtf((float)(cnt_src[base + 1] + 1)); }
  if (base + 2 < n) { off[base + 2] = e2; dinv[base + 2] = rsqrtf((float)(cnt_src[base + 2] + 1)); }
  if (base + 3 < n) { off[base + 3] = e3; dinv[base + 3] = rsqrtf((float)(cnt_src[base + 3] + 1)); }
}

// ================= fill (no atomics: rank precomputed) =================
__global__ void __launch_bounds__(256) fill_k(
    const int* __restrict__ esrc, const int* __restrict__ etgt, int E,
    const int* __restrict__ a2f, int N,
    const int* __restrict__ fsrc, const int* __restrict__ ftgt, int FE,
    const int* __restrict__ off_tgt, const int* __restrict__ rank_tgt,
    const int* __restrict__ off_a2f, const int* __restrict__ rank_a2f,
    const int* __restrict__ off_fe, const int* __restrict__ rank_fe,
    int* __restrict__ csr_src, int* __restrict__ aids, int* __restrict__ csr_fs) {
  int i = blockIdx.x * 256 + threadIdx.x;
  if (i < E) {
    csr_src[off_tgt[etgt[i]] + rank_tgt[i]] = esrc[i];
  } else if (i < E + N) {
    int j = i - E;
    aids[off_a2f[a2f[j]] + rank_a2f[j]] = j;
  } else if (i < E + N + FE) {
    int e = i - E - N;
    csr_fs[off_fe[ftgt[e]] + rank_fe[e]] = fsrc[e];
  }
}

// ===== edge gather: one WAVE per target row =====
// 64 lanes = 4 neighbor-slots (j) x 16 (l15). Near-uniform loop bound across the wave,
// 8 row-loads in flight (2-deep unroll x 4 slots). Cross-slot reduce via shfl_xor.
// out[t] = dinv[t] * (h'[t] + sum_s h'[s]) ; h' = dinv*h bf16
__global__ void __launch_bounds__(256) edge_gather_k(
    const int* __restrict__ off, const int* __restrict__ cnt,
    const int* __restrict__ csr_src, const unsigned short* __restrict__ h,
    const float* __restrict__ dinv, float* __restrict__ out, int n) {
  int tn = blockIdx.x * 4 + (threadIdx.x >> 6);
  if (tn >= n) return;
  int lane = threadIdx.x & 63;
  int j = lane >> 4, l15 = lane & 15;
  const ushort8_t* h8 = reinterpret_cast<const ushort8_t*>(h);

  float acc[8];
  if (j == 0) {
    ushort8_t hv = h8[(size_t)tn * 16 + l15];  // self term
#pragma unroll
    for (int e = 0; e < 8; e++) acc[e] = bf2f(hv[e]);
  } else {
#pragma unroll
    for (int e = 0; e < 8; e++) acc[e] = 0.f;
  }

  int s0 = off[tn], c = cnt[tn];
  int i = j;
  for (; i + 4 < c; i += 8) {
    int sa = csr_src[s0 + i];        // broadcast within 16-lane group
    int sb = csr_src[s0 + i + 4];
    ushort8_t va = h8[(size_t)sa * 16 + l15];
    ushort8_t vb = h8[(size_t)sb * 16 + l15];
#pragma unroll
    for (int e = 0; e < 8; e++) acc[e] += bf2f(va[e]) + bf2f(vb[e]);
  }
  if (i < c) {
    int sa = csr_src[s0 + i];
    ushort8_t va = h8[(size_t)sa * 16 + l15];
#pragma unroll
    for (int e = 0; e < 8; e++) acc[e] += bf2f(va[e]);
  }

  // butterfly reduce across the 4 slots (lanes 16 and 32 apart)
#pragma unroll
  for (int e = 0; e < 8; e++) {
    acc[e] += __shfl_xor(acc[e], 16, 64);
    acc[e] += __shfl_xor(acc[e], 32, 64);
  }

  if (j == 0) {
    float dt = dinv[tn];
    float4* o4 = reinterpret_cast<float4*>(out) + (size_t)tn * 32 + l15 * 2;
    o4[0] = make_float4(acc[0] * dt, acc[1] * dt, acc[2] * dt, acc[3] * dt);
    o4[1] = make_float4(acc[4] * dt, acc[5] * dt, acc[6] * dt, acc[7] * dt);
  }
}

// dst[f] = sum_{a in group f} src_rows[a]  (f32 rows)
__global__ void __launch_bounds__(256) seg_gather_k(
    const int* __restrict__ off, const int* __restrict__ cnt,
    const int* __restrict__ ids, const float* __restrict__ src_rows,
    float* __restrict__ dst, int n) {
  int f = blockIdx.x * 8 + (threadIdx.x >> 5);
  if (f >= n) return;
  int lane = threadIdx.x & 31;
  const float4* s4 = reinterpret_cast<const float4*>(src_rows);
  float ax = 0.f, ay = 0.f, az = 0.f, aw = 0.f;
  int s0 = off[f], c = cnt[f];
  int i = 0;
  for (; i + 2 <= c; i += 2) {
    int a1 = ids[s0 + i], a2 = ids[s0 + i + 1];
    float4 v1 = s4[(size_t)a1 * 32 + lane];
    float4 v2 = s4[(size_t)a2 * 32 + lane];
    ax += v1.x + v2.x; ay += v1.y + v2.y; az += v1.z + v2.z; aw += v1.w + v2.w;
  }
  if (i < c) {
    int a1 = ids[s0 + i];
    float4 v1 = s4[(size_t)a1 * 32 + lane];
    ax += v1.x; ay += v1.y; az += v1.z; aw += v1.w;
  }
  reinterpret_cast<float4*>(dst)[(size_t)f * 32 + lane] = make_float4(ax, ay, az, aw);
}

// ===== fused MLP: out = relu(fs@W1+b1)@W2+b2 ; 32 rows/block, hid in LDS =====
__global__ void __launch_bounds__(256) mlp_k(
    const float* __restrict__ fs, const float* __restrict__ W1,
    const float* __restrict__ b1, const float* __restrict__ W2,
    const float* __restrict__ b2, float* __restrict__ out, int nrows) {
  __shared__ float xs[32 * 128];  // 16 KB
  __shared__ float hs[32 * 256];  // 32 KB
  const int tid = threadIdx.x;
  const int rbase = blockIdx.x * 32;

  const float4* in4 = reinterpret_cast<const float4*>(fs);
  for (int idx = tid; idx < 32 * 32; idx += 256) {
    int r = idx / 32, kk = idx % 32;
    int gr = rbase + r;
    float4 v = make_float4(0.f, 0.f, 0.f, 0.f);
    if (gr < nrows) v = in4[(size_t)gr * 32 + kk];
    reinterpret_cast<float4*>(xs)[idx] = v;
  }
  __syncthreads();

  {
    float acc[32];
    float b = b1[tid];
#pragma unroll
    for (int m = 0; m < 32; m++) acc[m] = b;
#pragma unroll 4
    for (int k = 0; k < 128; k++) {
      float w = W1[k * 256 + tid];
#pragma unroll
      for (int m = 0; m < 32; m++) acc[m] += xs[m * 128 + k] * w;
    }
#pragma unroll
    for (int m = 0; m < 32; m++) hs[m * 256 + tid] = fmaxf(acc[m], 0.f);
  }
  __syncthreads();

  {
    const int c2 = tid & 127;
    const int g = tid >> 7;
    float acc[16];
    float b = b2[c2];
#pragma unroll
    for (int m = 0; m < 16; m++) acc[m] = b;
#pragma unroll 4
    for (int k = 0; k < 256; k++) {
      float w = W2[k * 128 + c2];
#pragma unroll
      for (int m = 0; m < 16; m++) acc[m] += hs[(g + m * 2) * 256 + k] * w;
    }
#pragma unroll
    for (int m = 0; m < 16; m++) {
      int gr = rbase + g + m * 2;
      if (gr < nrows) out[(size_t)gr * 128 + c2] = acc[m];
    }
  }
}

// ================= launch =================
extern "C" void kernel_launch(void* const* d_in, const int* in_sizes, int n_in,
                              void* d_out, int out_size, void* d_ws, size_t ws_size,
                              hipStream_t stream) {
  const float* x_atoms    = (const float*)d_in[0];
  const int*   edge_index = (const int*)d_in[1];
  // d_in[2] edge_attr: dead in reference — never read.
  const int*   frag_index = (const int*)d_in[3];
  // d_in[4] x_frags: values unused.
  const int*   a2f     = (const int*)d_in[5];
  const float* atom_w  = (const float*)d_in[6];
  const float* atom_b  = (const float*)d_in[7];
  // d_in[8..9] edge_w/edge_b: unused.
  const float* frag_w1 = (const float*)d_in[10];
  const float* frag_b1 = (const float*)d_in[11];
  const float* frag_w2 = (const float*)d_in[12];
  const float* frag_b2 = (const float*)d_in[13];

  const int N  = in_sizes[0] / DD;   // 100000
  const int E  = in_sizes[1] / 2;    // 1600000
  const int FE = in_sizes[3] / 2;    // 80000
  const int NF = in_sizes[4] / DD;   // 10000

  const int* esrc = edge_index;
  const int* etgt = edge_index + E;
  const int* fsrc = frag_index;
  const int* ftgt = frag_index + FE;

  float* out_atoms = (float*)d_out;
  float* out_frags = out_atoms + (size_t)N * DD;

  char* ws = (char*)d_ws;
  size_t off_b = 0;
  auto alloc = [&](size_t bytes) {
    void* p = ws + off_b;
    off_b += (bytes + 255) & ~(size_t)255;
    return p;
  };
  unsigned short* h = (unsigned short*)alloc((size_t)N * DD * 2);  // 25.6 MB bf16
  float* dinv     = (float*)alloc((size_t)N * 4);
  int*   cnts     = (int*)alloc(((size_t)2 * N + 2 * NF) * 4);  // one zeroed block
  int*   cnt_src  = cnts;
  int*   cnt_tgt  = cnts + N;
  int*   cnt_a2f  = cnts + 2 * N;
  int*   cnt_fe   = cnts + 2 * N + NF;
  int*   off_tgt  = (int*)alloc((size_t)N * 4);
  int*   rank_tgt = (int*)alloc((size_t)E * 4);
  int*   csr_src  = (int*)alloc((size_t)E * 4);
  int*   off_a2f  = (int*)alloc((size_t)NF * 4);
  int*   rank_a2f = (int*)alloc((size_t)N * 4);
  int*   aids     = (int*)alloc((size_t)N * 4);
  int*   off_fe   = (int*)alloc((size_t)NF * 4);
  int*   rank_fe  = (int*)alloc((size_t)FE * 4);
  int*   csr_fs   = (int*)alloc((size_t)FE * 4);
  int*   bsums    = (int*)alloc(1024 * 4);
  float* ff       = (float*)alloc((size_t)NF * DD * 4);
  float* fs       = (float*)alloc((size_t)NF * DD * 4);

  hipMemsetAsync(cnts, 0, ((size_t)2 * N + 2 * NF) * 4, stream);

  // counts/ranks (lean, full occupancy)
  int nb_cnt = (E + N + FE + 255) / 256;
  counts_k<<<nb_cnt, 256, 0, stream>>>(
      esrc, etgt, E, a2f, N, ftgt, FE,
      cnt_src, cnt_tgt, cnt_a2f, cnt_fe, rank_tgt, rank_a2f, rank_fe);

  // scans
  int nb1 = (N + 1023) / 1024;
  scanA_k<<<nb1 + 2, 256, 0, stream>>>(cnt_tgt, N, nb1, bsums,
                                       cnt_a2f, off_a2f, cnt_fe, off_fe, NF);
  scanB_k<<<nb1, 256, 0, stream>>>(cnt_tgt, N, bsums, off_tgt, cnt_src, dinv);

  // h' = bf16((x @ W + b) * dinv)   (dinv folded free into epilogue)
  mfma_h_k<<<(N + 127) / 128, 256, 0, stream>>>(x_atoms, atom_w, atom_b, dinv, h, N);

  // fill (atomic-free)
  fill_k<<<nb_cnt, 256, 0, stream>>>(
      esrc, etgt, E, a2f, N, fsrc, ftgt, FE,
      off_tgt, rank_tgt, off_a2f, rank_a2f, off_fe, rank_fe,
      csr_src, aids, csr_fs);

  // gathers
  edge_gather_k<<<(N + 3) / 4, 256, 0, stream>>>(off_tgt, cnt_tgt, csr_src, h, dinv, out_atoms, N);
  seg_gather_k<<<(NF + 7) / 8, 256, 0, stream>>>(off_a2f, cnt_a2f, aids, out_atoms, ff, NF);
  seg_gather_k<<<(NF + 7) / 8, 256, 0, stream>>>(off_fe, cnt_fe, csr_fs, ff, fs, NF);

  // fused MLP (f32)
  mlp_k<<<(NF + 31) / 32, 256, 0, stream>>>(fs, frag_w1, frag_b1, frag_w2, frag_b2, out_frags, NF);
}

// Round 8
// 416.600 us; speedup vs baseline: 1.0256x; 1.0256x over previous
//
#include <hip/hip_runtime.h>

constexpr int DD = 128;

typedef __attribute__((ext_vector_type(8))) short short8_t;   // 8 bf16 = 4 VGPR
typedef __attribute__((ext_vector_type(4))) float f32x4;

__device__ __forceinline__ float bf2f(unsigned short u) {
  union { unsigned int i; float f; } c;
  c.i = ((unsigned int)u) << 16;
  return c.f;
}
__device__ __forceinline__ unsigned short f2bf(float f) {
  union { float f; unsigned int i; } c;
  c.f = f;
  unsigned int x = c.i;
  x += 0x7fff + ((x >> 16) & 1);  // RNE
  return (unsigned short)(x >> 16);
}

// ================= counts (lean: no LDS, low VGPR, full occupancy) =================
__global__ void __launch_bounds__(256) counts_k(
    const int* __restrict__ esrc, const int* __restrict__ etgt, int E,
    const int* __restrict__ a2f, int N, const int* __restrict__ ftgt, int FE,
    int* __restrict__ cnt_src, int* __restrict__ cnt_tgt,
    int* __restrict__ cnt_a2f, int* __restrict__ cnt_fe,
    int* __restrict__ rank_tgt, int* __restrict__ rank_a2f, int* __restrict__ rank_fe) {
  int i = blockIdx.x * 256 + threadIdx.x;
  if (i < E) {
    atomicAdd(&cnt_src[esrc[i]], 1);
    rank_tgt[i] = atomicAdd(&cnt_tgt[etgt[i]], 1);
  } else if (i < E + N) {
    int j = i - E;
    rank_a2f[j] = atomicAdd(&cnt_a2f[a2f[j]], 1);
  } else if (i < E + N + FE) {
    int e = i - E - N;
    rank_fe[e] = atomicAdd(&cnt_fe[ftgt[e]], 1);
  }
}

// ====== MFMA GEMM: h' = bf16((x @ W + b) * dinv[row])  (scale free in epilogue) ======
__global__ void __launch_bounds__(256) mfma_h_k(
    const float* __restrict__ x, const float* __restrict__ W,
    const float* __restrict__ bias, const float* __restrict__ dinv,
    unsigned short* __restrict__ hout, int nrows) {
  __shared__ unsigned int wt[8192];  // 128 cols x 64 dwords, swizzled

  const int tid = threadIdx.x;
  const int rbase = blockIdx.x * 128;

  {  // stage Wt[c][k] = bf16(W[k][c]), dword-packed (k even|odd), swizzled
    int c = tid & 127;
    int half = tid >> 7;
#pragma unroll 4
    for (int j = 0; j < 32; j++) {
      int p = j * 2 + half;  // dword index = k/2
      int k = p * 2;
      float w0 = W[k * 128 + c];
      float w1 = W[(k + 1) * 128 + c];
      unsigned int packed = (unsigned int)f2bf(w0) | ((unsigned int)f2bf(w1) << 16);
      wt[(64 * c + p) ^ ((c & 7) << 2)] = packed;
    }
  }

  const int wave = tid >> 6;
  const int lane = tid & 63;
  const int l15 = lane & 15;
  const int kg = lane >> 4;

  float bcol[8];
#pragma unroll
  for (int ct = 0; ct < 8; ct++) bcol[ct] = bias[ct * 16 + l15];
  float dv[8];
#pragma unroll
  for (int rt = 0; rt < 2; rt++)
#pragma unroll
    for (int i = 0; i < 4; i++) {
      int gr = rbase + wave * 32 + rt * 16 + kg * 4 + i;
      dv[rt * 4 + i] = (gr < nrows) ? dinv[gr] : 0.f;
    }

  __syncthreads();

  f32x4 acc[2][8];
#pragma unroll
  for (int rt = 0; rt < 2; rt++)
#pragma unroll
    for (int ct = 0; ct < 8; ct++) acc[rt][ct] = (f32x4)(0.f);

#pragma unroll
  for (int ks = 0; ks < 4; ks++) {
    int kcol = ks * 32 + kg * 8;
    short8_t a[2];
#pragma unroll
    for (int rt = 0; rt < 2; rt++) {
      int row = rbase + wave * 32 + rt * 16 + l15;
      if (row < nrows) {
        const float4* xr = reinterpret_cast<const float4*>(x + (size_t)row * 128 + kcol);
        float4 v0 = xr[0], v1 = xr[1];
        a[rt][0] = (short)f2bf(v0.x); a[rt][1] = (short)f2bf(v0.y);
        a[rt][2] = (short)f2bf(v0.z); a[rt][3] = (short)f2bf(v0.w);
        a[rt][4] = (short)f2bf(v1.x); a[rt][5] = (short)f2bf(v1.y);
        a[rt][6] = (short)f2bf(v1.z); a[rt][7] = (short)f2bf(v1.w);
      } else {
#pragma unroll
        for (int e = 0; e < 8; e++) a[rt][e] = 0;
      }
    }
#pragma unroll
    for (int ct = 0; ct < 8; ct++) {
      int col = ct * 16 + l15;
      int dw0 = (64 * col + ks * 16 + kg * 4) ^ ((col & 7) << 2);
      short8_t b = *reinterpret_cast<const short8_t*>(&wt[dw0]);
      acc[0][ct] = __builtin_amdgcn_mfma_f32_16x16x32_bf16(a[0], b, acc[0][ct], 0, 0, 0);
      acc[1][ct] = __builtin_amdgcn_mfma_f32_16x16x32_bf16(a[1], b, acc[1][ct], 0, 0, 0);
    }
  }

#pragma unroll
  for (int rt = 0; rt < 2; rt++)
#pragma unroll
    for (int ct = 0; ct < 8; ct++)
#pragma unroll
      for (int i = 0; i < 4; i++) {
        int gr = rbase + wave * 32 + rt * 16 + kg * 4 + i;
        if (gr < nrows)
          hout[(size_t)gr * 128 + ct * 16 + l15] =
              f2bf((acc[rt][ct][i] + bcol[ct]) * dv[rt * 4 + i]);
      }
}

// ================= Linear f32 (frag MLP, small) =================
template<int IC, int OC, bool RELU, int RPT>
__global__ void __launch_bounds__(256) linear_k(
    const float* __restrict__ in, const float* __restrict__ W,
    const float* __restrict__ bias, float* __restrict__ out, int nrows) {
  constexpr int GROUPS = 256 / OC;
  constexpr int RBLK = RPT * GROUPS;
  __shared__ float xs[RBLK * IC];
  const int tid = threadIdx.x;
  const int c = tid % OC;
  const int g = tid / OC;
  const int rbase = blockIdx.x * RBLK;

  constexpr int NV = RBLK * IC / 4;
  const float4* in4 = reinterpret_cast<const float4*>(in);
  for (int idx = tid; idx < NV; idx += 256) {
    int r = idx / (IC / 4);
    int kk = idx % (IC / 4);
    int gr = rbase + r;
    float4 v = make_float4(0.f, 0.f, 0.f, 0.f);
    if (gr < nrows) v = in4[(size_t)gr * (IC / 4) + kk];
    reinterpret_cast<float4*>(xs)[idx] = v;
  }
  __syncthreads();

  float acc[RPT];
  float b = bias[c];
#pragma unroll
  for (int m = 0; m < RPT; m++) acc[m] = b;

#pragma unroll 4
  for (int k = 0; k < IC; k++) {
    float w = W[k * OC + c];
#pragma unroll
    for (int m = 0; m < RPT; m++)
      acc[m] += xs[(g + m * GROUPS) * IC + k] * w;
  }

#pragma unroll
  for (int m = 0; m < RPT; m++) {
    int gr = rbase + g + m * GROUPS;
    if (gr < nrows) {
      float v = acc[m];
      if (RELU) v = fmaxf(v, 0.f);
      out[(size_t)gr * OC + c] = v;
    }
  }
}

// ===== scanA: blocks [0,nb): block sums of cnt_tgt; block nb: a2f scan; nb+1: fe scan =====
__global__ void __launch_bounds__(256) scanA_k(
    const int* __restrict__ cnt_tgt, int n, int nb, int* __restrict__ bsums,
    const int* __restrict__ cnt_a2f, int* __restrict__ off_a2f,
    const int* __restrict__ cnt_fe, int* __restrict__ off_fe, int nf) {
  __shared__ int s[256];
  int t = threadIdx.x;
  int bid = blockIdx.x;
  if (bid < nb) {
    int base = bid * 1024;
    int v = 0;
    for (int i = t; i < 1024; i += 256) {
      int g = base + i;
      if (g < n) v += cnt_tgt[g];
    }
    s[t] = v;
    __syncthreads();
    for (int d = 128; d > 0; d >>= 1) {
      if (t < d) s[t] += s[t + d];
      __syncthreads();
    }
    if (t == 0) bsums[bid] = s[0];
  } else {
    const int* in = (bid == nb) ? cnt_a2f : cnt_fe;
    int* off = (bid == nb) ? off_a2f : off_fe;
    int carry = 0;
    for (int base = 0; base < nf; base += 256) {
      int v = (base + t < nf) ? in[base + t] : 0;
      __syncthreads();
      s[t] = v;
      __syncthreads();
      for (int d = 1; d < 256; d <<= 1) {
        int u = (t >= d) ? s[t - d] : 0;
        __syncthreads();
        s[t] += u;
        __syncthreads();
      }
      if (base + t < nf) off[base + t] = s[t] - v + carry;
      carry += s[255];
    }
  }
}

// ===== scanB: exclusive scan cnt_tgt -> off_tgt (prefix from bsums inline) + dinv =====
__global__ void __launch_bounds__(256) scanB_k(
    const int* __restrict__ in, int n, const int* __restrict__ bsums,
    int* __restrict__ off, const int* __restrict__ cnt_src,
    float* __restrict__ dinv) {
  __shared__ int s[256];
  int t = threadIdx.x;
  int bid = blockIdx.x;
  s[t] = (t < bid) ? bsums[t] : 0;  // nb <= 256
  __syncthreads();
  for (int d = 128; d > 0; d >>= 1) {
    if (t < d) s[t] += s[t + d];
    __syncthreads();
  }
  int prefix = s[0];
  __syncthreads();

  int base = bid * 1024 + t * 4;
  int a0 = (base + 0 < n) ? in[base + 0] : 0;
  int a1 = (base + 1 < n) ? in[base + 1] : 0;
  int a2 = (base + 2 < n) ? in[base + 2] : 0;
  int a3 = (base + 3 < n) ? in[base + 3] : 0;
  int tot = a0 + a1 + a2 + a3;
  s[t] = tot;
  __syncthreads();
  for (int d = 1; d < 256; d <<= 1) {
    int u = (t >= d) ? s[t - d] : 0;
    __syncthreads();
    s[t] += u;
    __syncthreads();
  }
  int pre = s[t] - tot + prefix;
  int e0 = pre, e1 = pre + a0, e2 = e1 + a1, e3 = e2 + a2;
  if (base + 0 < n) { off[base + 0] = e0; dinv[base + 0] = rsqrtf((float)(cnt_src[base + 0] + 1)); }
  if (base + 1 < n) { off[base + 1] = e1; dinv[base + 1] = rsqrtf((float)(cnt_src[base + 1] + 1)); }
  if (base + 2 < n) { off[base + 2] = e2; dinv[base + 2] = rsqrtf((float)(cnt_src[base + 2] + 1)); }
  if (base + 3 < n) { off[base + 3] = e3; dinv[base + 3] = rsqrtf((float)(cnt_src[base + 3] + 1)); }
}

// ================= fill (no atomics: rank precomputed) =================
__global__ void __launch_bounds__(256) fill_k(
    const int* __restrict__ esrc, const int* __restrict__ etgt, int E,
    const int* __restrict__ a2f, int N,
    const int* __restrict__ fsrc, const int* __restrict__ ftgt, int FE,
    const int* __restrict__ off_tgt, const int* __restrict__ rank_tgt,
    const int* __restrict__ off_a2f, const int* __restrict__ rank_a2f,
    const int* __restrict__ off_fe, const int* __restrict__ rank_fe,
    int* __restrict__ csr_src, int* __restrict__ aids, int* __restrict__ csr_fs) {
  int i = blockIdx.x * 256 + threadIdx.x;
  if (i < E) {
    csr_src[off_tgt[etgt[i]] + rank_tgt[i]] = esrc[i];
  } else if (i < E + N) {
    int j = i - E;
    aids[off_a2f[a2f[j]] + rank_a2f[j]] = j;
  } else if (i < E + N + FE) {
    int e = i - E - N;
    csr_fs[off_fe[ftgt[e]] + rank_fe[e]] = fsrc[e];
  }
}

// ===== edge gather (R4-proven): out[t] = dinv[t]*(h'[t] + sum_s h'[s]); h' = dinv*h bf16 =====
__global__ void __launch_bounds__(256) edge_gather_k(
    const int* __restrict__ off, const int* __restrict__ cnt,
    const int* __restrict__ csr_src, const unsigned short* __restrict__ h,
    const float* __restrict__ dinv, float* __restrict__ out, int n) {
  int tn = blockIdx.x * 8 + (threadIdx.x >> 5);
  if (tn >= n) return;
  int lane = threadIdx.x & 31;
  const ushort4* h4 = reinterpret_cast<const ushort4*>(h);
  ushort4 hv = h4[(size_t)tn * 32 + lane];
  float ax = bf2f(hv.x), ay = bf2f(hv.y), az = bf2f(hv.z), aw = bf2f(hv.w);
  int s0 = off[tn], c = cnt[tn];
  int i = 0;
  for (; i + 4 <= c; i += 4) {
    int s1 = csr_src[s0 + i + 0];
    int s2 = csr_src[s0 + i + 1];
    int s3 = csr_src[s0 + i + 2];
    int s4 = csr_src[s0 + i + 3];
    ushort4 v1 = h4[(size_t)s1 * 32 + lane];
    ushort4 v2 = h4[(size_t)s2 * 32 + lane];
    ushort4 v3 = h4[(size_t)s3 * 32 + lane];
    ushort4 v4 = h4[(size_t)s4 * 32 + lane];
    ax += (bf2f(v1.x) + bf2f(v2.x)) + (bf2f(v3.x) + bf2f(v4.x));
    ay += (bf2f(v1.y) + bf2f(v2.y)) + (bf2f(v3.y) + bf2f(v4.y));
    az += (bf2f(v1.z) + bf2f(v2.z)) + (bf2f(v3.z) + bf2f(v4.z));
    aw += (bf2f(v1.w) + bf2f(v2.w)) + (bf2f(v3.w) + bf2f(v4.w));
  }
  for (; i < c; i++) {
    int s1 = csr_src[s0 + i];
    ushort4 v1 = h4[(size_t)s1 * 32 + lane];
    ax += bf2f(v1.x); ay += bf2f(v1.y); az += bf2f(v1.z); aw += bf2f(v1.w);
  }
  float dt = dinv[tn];
  reinterpret_cast<float4*>(out)[(size_t)tn * 32 + lane] =
      make_float4(ax * dt, ay * dt, az * dt, aw * dt);
}

// dst[f] = sum_{a in group f} src_rows[a]  (f32 rows)
__global__ void __launch_bounds__(256) seg_gather_k(
    const int* __restrict__ off, const int* __restrict__ cnt,
    const int* __restrict__ ids, const float* __restrict__ src_rows,
    float* __restrict__ dst, int n) {
  int f = blockIdx.x * 8 + (threadIdx.x >> 5);
  if (f >= n) return;
  int lane = threadIdx.x & 31;
  const float4* s4 = reinterpret_cast<const float4*>(src_rows);
  float ax = 0.f, ay = 0.f, az = 0.f, aw = 0.f;
  int s0 = off[f], c = cnt[f];
  int i = 0;
  for (; i + 2 <= c; i += 2) {
    int a1 = ids[s0 + i], a2 = ids[s0 + i + 1];
    float4 v1 = s4[(size_t)a1 * 32 + lane];
    float4 v2 = s4[(size_t)a2 * 32 + lane];
    ax += v1.x + v2.x; ay += v1.y + v2.y; az += v1.z + v2.z; aw += v1.w + v2.w;
  }
  if (i < c) {
    int a1 = ids[s0 + i];
    float4 v1 = s4[(size_t)a1 * 32 + lane];
    ax += v1.x; ay += v1.y; az += v1.z; aw += v1.w;
  }
  reinterpret_cast<float4*>(dst)[(size_t)f * 32 + lane] = make_float4(ax, ay, az, aw);
}

// ================= launch =================
extern "C" void kernel_launch(void* const* d_in, const int* in_sizes, int n_in,
                              void* d_out, int out_size, void* d_ws, size_t ws_size,
                              hipStream_t stream) {
  const float* x_atoms    = (const float*)d_in[0];
  const int*   edge_index = (const int*)d_in[1];
  // d_in[2] edge_attr: dead in reference — never read.
  const int*   frag_index = (const int*)d_in[3];
  // d_in[4] x_frags: values unused.
  const int*   a2f     = (const int*)d_in[5];
  const float* atom_w  = (const float*)d_in[6];
  const float* atom_b  = (const float*)d_in[7];
  // d_in[8..9] edge_w/edge_b: unused.
  const float* frag_w1 = (const float*)d_in[10];
  const float* frag_b1 = (const float*)d_in[11];
  const float* frag_w2 = (const float*)d_in[12];
  const float* frag_b2 = (const float*)d_in[13];

  const int N  = in_sizes[0] / DD;   // 100000
  const int E  = in_sizes[1] / 2;    // 1600000
  const int FE = in_sizes[3] / 2;    // 80000
  const int NF = in_sizes[4] / DD;   // 10000

  const int* esrc = edge_index;
  const int* etgt = edge_index + E;
  const int* fsrc = frag_index;
  const int* ftgt = frag_index + FE;

  float* out_atoms = (float*)d_out;
  float* out_frags = out_atoms + (size_t)N * DD;

  char* ws = (char*)d_ws;
  size_t off_b = 0;
  auto alloc = [&](size_t bytes) {
    void* p = ws + off_b;
    off_b += (bytes + 255) & ~(size_t)255;
    return p;
  };
  unsigned short* h = (unsigned short*)alloc((size_t)N * DD * 2);  // 25.6 MB bf16
  float* dinv     = (float*)alloc((size_t)N * 4);
  int*   cnts     = (int*)alloc(((size_t)2 * N + 2 * NF) * 4);  // one zeroed block
  int*   cnt_src  = cnts;
  int*   cnt_tgt  = cnts + N;
  int*   cnt_a2f  = cnts + 2 * N;
  int*   cnt_fe   = cnts + 2 * N + NF;
  int*   off_tgt  = (int*)alloc((size_t)N * 4);
  int*   rank_tgt = (int*)alloc((size_t)E * 4);
  int*   csr_src  = (int*)alloc((size_t)E * 4);
  int*   off_a2f  = (int*)alloc((size_t)NF * 4);
  int*   rank_a2f = (int*)alloc((size_t)N * 4);
  int*   aids     = (int*)alloc((size_t)N * 4);
  int*   off_fe   = (int*)alloc((size_t)NF * 4);
  int*   rank_fe  = (int*)alloc((size_t)FE * 4);
  int*   csr_fs   = (int*)alloc((size_t)FE * 4);
  int*   bsums    = (int*)alloc(1024 * 4);
  float* ff       = (float*)alloc((size_t)NF * DD * 4);
  float* fs       = (float*)alloc((size_t)NF * DD * 4);
  float* hid      = (float*)alloc((size_t)NF * 2 * DD * 4);

  hipMemsetAsync(cnts, 0, ((size_t)2 * N + 2 * NF) * 4, stream);

  // counts/ranks (lean, full occupancy)
  int nb_cnt = (E + N + FE + 255) / 256;
  counts_k<<<nb_cnt, 256, 0, stream>>>(
      esrc, etgt, E, a2f, N, ftgt, FE,
      cnt_src, cnt_tgt, cnt_a2f, cnt_fe, rank_tgt, rank_a2f, rank_fe);

  // scans (2 dispatches)
  int nb1 = (N + 1023) / 1024;
  scanA_k<<<nb1 + 2, 256, 0, stream>>>(cnt_tgt, N, nb1, bsums,
                                       cnt_a2f, off_a2f, cnt_fe, off_fe, NF);
  scanB_k<<<nb1, 256, 0, stream>>>(cnt_tgt, N, bsums, off_tgt, cnt_src, dinv);

  // h' = bf16((x @ W + b) * dinv)
  mfma_h_k<<<(N + 127) / 128, 256, 0, stream>>>(x_atoms, atom_w, atom_b, dinv, h, N);

  // fill (atomic-free)
  fill_k<<<nb_cnt, 256, 0, stream>>>(
      esrc, etgt, E, a2f, N, fsrc, ftgt, FE,
      off_tgt, rank_tgt, off_a2f, rank_a2f, off_fe, rank_fe,
      csr_src, aids, csr_fs);

  // gathers
  edge_gather_k<<<(N + 7) / 8, 256, 0, stream>>>(off_tgt, cnt_tgt, csr_src, h, dinv, out_atoms, N);
  seg_gather_k<<<(NF + 7) / 8, 256, 0, stream>>>(off_a2f, cnt_a2f, aids, out_atoms, ff, NF);
  seg_gather_k<<<(NF + 7) / 8, 256, 0, stream>>>(off_fe, cnt_fe, csr_fs, ff, fs, NF);

  // MLP (f32, two proven dispatches)
  linear_k<128, 256, true, 32><<<(NF + 31) / 32, 256, 0, stream>>>(fs, frag_w1, frag_b1, hid, NF);
  linear_k<256, 128, false, 16><<<(NF + 31) / 32, 256, 0, stream>>>(hid, frag_w2, frag_b2, out_frags, NF);
}

// Round 9
// 391.507 us; speedup vs baseline: 1.0913x; 1.0641x over previous
//
#include <hip/hip_runtime.h>

constexpr int DD = 128;

typedef __attribute__((ext_vector_type(8))) short short8_t;   // 8 bf16 = 4 VGPR
typedef __attribute__((ext_vector_type(4))) float f32x4;

__device__ __forceinline__ float bf2f(unsigned short u) {
  union { unsigned int i; float f; } c;
  c.i = ((unsigned int)u) << 16;
  return c.f;
}
__device__ __forceinline__ unsigned short f2bf(float f) {
  union { float f; unsigned int i; } c;
  c.f = f;
  unsigned int x = c.i;
  x += 0x7fff + ((x >> 16) & 1);  // RNE
  return (unsigned short)(x >> 16);
}

// ================= counts (lean: no LDS, low VGPR, full occupancy) =================
__global__ void __launch_bounds__(256) counts_k(
    const int* __restrict__ esrc, const int* __restrict__ etgt, int E,
    const int* __restrict__ a2f, int N, const int* __restrict__ ftgt, int FE,
    int* __restrict__ cnt_src, int* __restrict__ cnt_tgt,
    int* __restrict__ cnt_a2f, int* __restrict__ cnt_fe,
    int* __restrict__ rank_tgt, int* __restrict__ rank_a2f, int* __restrict__ rank_fe) {
  int i = blockIdx.x * 256 + threadIdx.x;
  if (i < E) {
    atomicAdd(&cnt_src[esrc[i]], 1);
    rank_tgt[i] = atomicAdd(&cnt_tgt[etgt[i]], 1);
  } else if (i < E + N) {
    int j = i - E;
    rank_a2f[j] = atomicAdd(&cnt_a2f[a2f[j]], 1);
  } else if (i < E + N + FE) {
    int e = i - E - N;
    rank_fe[e] = atomicAdd(&cnt_fe[ftgt[e]], 1);
  }
}

// ====== MFMA GEMM: h' = bf16((x @ W + b) * dinv[row])  (scale free in epilogue) ======
__global__ void __launch_bounds__(256) mfma_h_k(
    const float* __restrict__ x, const float* __restrict__ W,
    const float* __restrict__ bias, const float* __restrict__ dinv,
    unsigned short* __restrict__ hout, int nrows) {
  __shared__ unsigned int wt[8192];  // 128 cols x 64 dwords, swizzled

  const int tid = threadIdx.x;
  const int rbase = blockIdx.x * 128;

  {  // stage Wt[c][k] = bf16(W[k][c]), dword-packed (k even|odd), swizzled
    int c = tid & 127;
    int half = tid >> 7;
#pragma unroll 4
    for (int j = 0; j < 32; j++) {
      int p = j * 2 + half;  // dword index = k/2
      int k = p * 2;
      float w0 = W[k * 128 + c];
      float w1 = W[(k + 1) * 128 + c];
      unsigned int packed = (unsigned int)f2bf(w0) | ((unsigned int)f2bf(w1) << 16);
      wt[(64 * c + p) ^ ((c & 7) << 2)] = packed;
    }
  }

  const int wave = tid >> 6;
  const int lane = tid & 63;
  const int l15 = lane & 15;
  const int kg = lane >> 4;

  float bcol[8];
#pragma unroll
  for (int ct = 0; ct < 8; ct++) bcol[ct] = bias[ct * 16 + l15];
  float dv[8];
#pragma unroll
  for (int rt = 0; rt < 2; rt++)
#pragma unroll
    for (int i = 0; i < 4; i++) {
      int gr = rbase + wave * 32 + rt * 16 + kg * 4 + i;
      dv[rt * 4 + i] = (gr < nrows) ? dinv[gr] : 0.f;
    }

  __syncthreads();

  f32x4 acc[2][8];
#pragma unroll
  for (int rt = 0; rt < 2; rt++)
#pragma unroll
    for (int ct = 0; ct < 8; ct++) acc[rt][ct] = (f32x4)(0.f);

#pragma unroll
  for (int ks = 0; ks < 4; ks++) {
    int kcol = ks * 32 + kg * 8;
    short8_t a[2];
#pragma unroll
    for (int rt = 0; rt < 2; rt++) {
      int row = rbase + wave * 32 + rt * 16 + l15;
      if (row < nrows) {
        const float4* xr = reinterpret_cast<const float4*>(x + (size_t)row * 128 + kcol);
        float4 v0 = xr[0], v1 = xr[1];
        a[rt][0] = (short)f2bf(v0.x); a[rt][1] = (short)f2bf(v0.y);
        a[rt][2] = (short)f2bf(v0.z); a[rt][3] = (short)f2bf(v0.w);
        a[rt][4] = (short)f2bf(v1.x); a[rt][5] = (short)f2bf(v1.y);
        a[rt][6] = (short)f2bf(v1.z); a[rt][7] = (short)f2bf(v1.w);
      } else {
#pragma unroll
        for (int e = 0; e < 8; e++) a[rt][e] = 0;
      }
    }
#pragma unroll
    for (int ct = 0; ct < 8; ct++) {
      int col = ct * 16 + l15;
      int dw0 = (64 * col + ks * 16 + kg * 4) ^ ((col & 7) << 2);
      short8_t b = *reinterpret_cast<const short8_t*>(&wt[dw0]);
      acc[0][ct] = __builtin_amdgcn_mfma_f32_16x16x32_bf16(a[0], b, acc[0][ct], 0, 0, 0);
      acc[1][ct] = __builtin_amdgcn_mfma_f32_16x16x32_bf16(a[1], b, acc[1][ct], 0, 0, 0);
    }
  }

#pragma unroll
  for (int rt = 0; rt < 2; rt++)
#pragma unroll
    for (int ct = 0; ct < 8; ct++)
#pragma unroll
      for (int i = 0; i < 4; i++) {
        int gr = rbase + wave * 32 + rt * 16 + kg * 4 + i;
        if (gr < nrows)
          hout[(size_t)gr * 128 + ct * 16 + l15] =
              f2bf((acc[rt][ct][i] + bcol[ct]) * dv[rt * 4 + i]);
      }
}

// ================= Linear f32 (frag MLP, small) =================
template<int IC, int OC, bool RELU, int RPT>
__global__ void __launch_bounds__(256) linear_k(
    const float* __restrict__ in, const float* __restrict__ W,
    const float* __restrict__ bias, float* __restrict__ out, int nrows) {
  constexpr int GROUPS = 256 / OC;
  constexpr int RBLK = RPT * GROUPS;
  __shared__ float xs[RBLK * IC];
  const int tid = threadIdx.x;
  const int c = tid % OC;
  const int g = tid / OC;
  const int rbase = blockIdx.x * RBLK;

  constexpr int NV = RBLK * IC / 4;
  const float4* in4 = reinterpret_cast<const float4*>(in);
  for (int idx = tid; idx < NV; idx += 256) {
    int r = idx / (IC / 4);
    int kk = idx % (IC / 4);
    int gr = rbase + r;
    float4 v = make_float4(0.f, 0.f, 0.f, 0.f);
    if (gr < nrows) v = in4[(size_t)gr * (IC / 4) + kk];
    reinterpret_cast<float4*>(xs)[idx] = v;
  }
  __syncthreads();

  float acc[RPT];
  float b = bias[c];
#pragma unroll
  for (int m = 0; m < RPT; m++) acc[m] = b;

#pragma unroll 4
  for (int k = 0; k < IC; k++) {
    float w = W[k * OC + c];
#pragma unroll
    for (int m = 0; m < RPT; m++)
      acc[m] += xs[(g + m * GROUPS) * IC + k] * w;
  }

#pragma unroll
  for (int m = 0; m < RPT; m++) {
    int gr = rbase + g + m * GROUPS;
    if (gr < nrows) {
      float v = acc[m];
      if (RELU) v = fmaxf(v, 0.f);
      out[(size_t)gr * OC + c] = v;
    }
  }
}

// ===== bsum1024: blocks [0,nb): 1024-thr tree-reduce of cnt_tgt chunk -> bsums;
//       blocks nb, nb+1: 1024-thr exclusive scans of the two 10k frag count arrays =====
__global__ void __launch_bounds__(1024) bsum1024_k(
    const int* __restrict__ cnt_tgt, int n, int nb, int* __restrict__ bsums,
    const int* __restrict__ cnt_a2f, int* __restrict__ off_a2f,
    const int* __restrict__ cnt_fe, int* __restrict__ off_fe, int nf) {
  __shared__ int s[1024];
  int t = threadIdx.x;
  int bid = blockIdx.x;
  if (bid < nb) {
    int g = bid * 1024 + t;
    s[t] = (g < n) ? cnt_tgt[g] : 0;
    __syncthreads();
    for (int d = 512; d > 0; d >>= 1) {
      if (t < d) s[t] += s[t + d];
      __syncthreads();
    }
    if (t == 0) bsums[bid] = s[0];
  } else {
    const int* in = (bid == nb) ? cnt_a2f : cnt_fe;
    int* off = (bid == nb) ? off_a2f : off_fe;
    int carry = 0;
    for (int base = 0; base < nf; base += 1024) {
      int v = (base + t < nf) ? in[base + t] : 0;
      __syncthreads();
      s[t] = v;
      __syncthreads();
      for (int d = 1; d < 1024; d <<= 1) {
        int u = (t >= d) ? s[t - d] : 0;
        __syncthreads();
        s[t] += u;
        __syncthreads();
      }
      int tot = s[1023];
      if (base + t < nf) off[base + t] = s[t] - v + carry;
      carry += tot;
    }
  }
}

// ===== scanB: exclusive scan cnt_tgt -> off_tgt (prefix from bsums inline) + dinv =====
__global__ void __launch_bounds__(256) scanB_k(
    const int* __restrict__ in, int n, const int* __restrict__ bsums,
    int* __restrict__ off, const int* __restrict__ cnt_src,
    float* __restrict__ dinv) {
  __shared__ int s[256];
  int t = threadIdx.x;
  int bid = blockIdx.x;
  s[t] = (t < bid) ? bsums[t] : 0;  // nb <= 256
  __syncthreads();
  for (int d = 128; d > 0; d >>= 1) {
    if (t < d) s[t] += s[t + d];
    __syncthreads();
  }
  int prefix = s[0];
  __syncthreads();

  int base = bid * 1024 + t * 4;
  int a0 = (base + 0 < n) ? in[base + 0] : 0;
  int a1 = (base + 1 < n) ? in[base + 1] : 0;
  int a2 = (base + 2 < n) ? in[base + 2] : 0;
  int a3 = (base + 3 < n) ? in[base + 3] : 0;
  int tot = a0 + a1 + a2 + a3;
  s[t] = tot;
  __syncthreads();
  for (int d = 1; d < 256; d <<= 1) {
    int u = (t >= d) ? s[t - d] : 0;
    __syncthreads();
    s[t] += u;
    __syncthreads();
  }
  int pre = s[t] - tot + prefix;
  int e0 = pre, e1 = pre + a0, e2 = e1 + a1, e3 = e2 + a2;
  if (base + 0 < n) { off[base + 0] = e0; dinv[base + 0] = rsqrtf((float)(cnt_src[base + 0] + 1)); }
  if (base + 1 < n) { off[base + 1] = e1; dinv[base + 1] = rsqrtf((float)(cnt_src[base + 1] + 1)); }
  if (base + 2 < n) { off[base + 2] = e2; dinv[base + 2] = rsqrtf((float)(cnt_src[base + 2] + 1)); }
  if (base + 3 < n) { off[base + 3] = e3; dinv[base + 3] = rsqrtf((float)(cnt_src[base + 3] + 1)); }
}

// ================= fill (no atomics: rank precomputed) =================
__global__ void __launch_bounds__(256) fill_k(
    const int* __restrict__ esrc, const int* __restrict__ etgt, int E,
    const int* __restrict__ a2f, int N,
    const int* __restrict__ fsrc, const int* __restrict__ ftgt, int FE,
    const int* __restrict__ off_tgt, const int* __restrict__ rank_tgt,
    const int* __restrict__ off_a2f, const int* __restrict__ rank_a2f,
    const int* __restrict__ off_fe, const int* __restrict__ rank_fe,
    int* __restrict__ csr_src, int* __restrict__ aids, int* __restrict__ csr_fs) {
  int i = blockIdx.x * 256 + threadIdx.x;
  if (i < E) {
    csr_src[off_tgt[etgt[i]] + rank_tgt[i]] = esrc[i];
  } else if (i < E + N) {
    int j = i - E;
    aids[off_a2f[a2f[j]] + rank_a2f[j]] = j;
  } else if (i < E + N + FE) {
    int e = i - E - N;
    csr_fs[off_fe[ftgt[e]] + rank_fe[e]] = fsrc[e];
  }
}

// ===== edge gather (R4-proven): out[t] = dinv[t]*(h'[t] + sum_s h'[s]); h' = dinv*h bf16 =====
__global__ void __launch_bounds__(256) edge_gather_k(
    const int* __restrict__ off, const int* __restrict__ cnt,
    const int* __restrict__ csr_src, const unsigned short* __restrict__ h,
    const float* __restrict__ dinv, float* __restrict__ out, int n) {
  int tn = blockIdx.x * 8 + (threadIdx.x >> 5);
  if (tn >= n) return;
  int lane = threadIdx.x & 31;
  const ushort4* h4 = reinterpret_cast<const ushort4*>(h);
  ushort4 hv = h4[(size_t)tn * 32 + lane];
  float ax = bf2f(hv.x), ay = bf2f(hv.y), az = bf2f(hv.z), aw = bf2f(hv.w);
  int s0 = off[tn], c = cnt[tn];
  int i = 0;
  for (; i + 4 <= c; i += 4) {
    int s1 = csr_src[s0 + i + 0];
    int s2 = csr_src[s0 + i + 1];
    int s3 = csr_src[s0 + i + 2];
    int s4 = csr_src[s0 + i + 3];
    ushort4 v1 = h4[(size_t)s1 * 32 + lane];
    ushort4 v2 = h4[(size_t)s2 * 32 + lane];
    ushort4 v3 = h4[(size_t)s3 * 32 + lane];
    ushort4 v4 = h4[(size_t)s4 * 32 + lane];
    ax += (bf2f(v1.x) + bf2f(v2.x)) + (bf2f(v3.x) + bf2f(v4.x));
    ay += (bf2f(v1.y) + bf2f(v2.y)) + (bf2f(v3.y) + bf2f(v4.y));
    az += (bf2f(v1.z) + bf2f(v2.z)) + (bf2f(v3.z) + bf2f(v4.z));
    aw += (bf2f(v1.w) + bf2f(v2.w)) + (bf2f(v3.w) + bf2f(v4.w));
  }
  for (; i < c; i++) {
    int s1 = csr_src[s0 + i];
    ushort4 v1 = h4[(size_t)s1 * 32 + lane];
    ax += bf2f(v1.x); ay += bf2f(v1.y); az += bf2f(v1.z); aw += bf2f(v1.w);
  }
  float dt = dinv[tn];
  reinterpret_cast<float4*>(out)[(size_t)tn * 32 + lane] =
      make_float4(ax * dt, ay * dt, az * dt, aw * dt);
}

// dst[f] = sum_{a in group f} src_rows[a]  (f32 rows)
__global__ void __launch_bounds__(256) seg_gather_k(
    const int* __restrict__ off, const int* __restrict__ cnt,
    const int* __restrict__ ids, const float* __restrict__ src_rows,
    float* __restrict__ dst, int n) {
  int f = blockIdx.x * 8 + (threadIdx.x >> 5);
  if (f >= n) return;
  int lane = threadIdx.x & 31;
  const float4* s4 = reinterpret_cast<const float4*>(src_rows);
  float ax = 0.f, ay = 0.f, az = 0.f, aw = 0.f;
  int s0 = off[f], c = cnt[f];
  int i = 0;
  for (; i + 2 <= c; i += 2) {
    int a1 = ids[s0 + i], a2 = ids[s0 + i + 1];
    float4 v1 = s4[(size_t)a1 * 32 + lane];
    float4 v2 = s4[(size_t)a2 * 32 + lane];
    ax += v1.x + v2.x; ay += v1.y + v2.y; az += v1.z + v2.z; aw += v1.w + v2.w;
  }
  if (i < c) {
    int a1 = ids[s0 + i];
    float4 v1 = s4[(size_t)a1 * 32 + lane];
    ax += v1.x; ay += v1.y; az += v1.z; aw += v1.w;
  }
  reinterpret_cast<float4*>(dst)[(size_t)f * 32 + lane] = make_float4(ax, ay, az, aw);
}

// ================= launch =================
extern "C" void kernel_launch(void* const* d_in, const int* in_sizes, int n_in,
                              void* d_out, int out_size, void* d_ws, size_t ws_size,
                              hipStream_t stream) {
  const float* x_atoms    = (const float*)d_in[0];
  const int*   edge_index = (const int*)d_in[1];
  // d_in[2] edge_attr: dead in reference — never read.
  const int*   frag_index = (const int*)d_in[3];
  // d_in[4] x_frags: values unused.
  const int*   a2f     = (const int*)d_in[5];
  const float* atom_w  = (const float*)d_in[6];
  const float* atom_b  = (const float*)d_in[7];
  // d_in[8..9] edge_w/edge_b: unused.
  const float* frag_w1 = (const float*)d_in[10];
  const float* frag_b1 = (const float*)d_in[11];
  const float* frag_w2 = (const float*)d_in[12];
  const float* frag_b2 = (const float*)d_in[13];

  const int N  = in_sizes[0] / DD;   // 100000
  const int E  = in_sizes[1] / 2;    // 1600000
  const int FE = in_sizes[3] / 2;    // 80000
  const int NF = in_sizes[4] / DD;   // 10000

  const int* esrc = edge_index;
  const int* etgt = edge_index + E;
  const int* fsrc = frag_index;
  const int* ftgt = frag_index + FE;

  float* out_atoms = (float*)d_out;
  float* out_frags = out_atoms + (size_t)N * DD;

  char* ws = (char*)d_ws;
  size_t off_b = 0;
  auto alloc = [&](size_t bytes) {
    void* p = ws + off_b;
    off_b += (bytes + 255) & ~(size_t)255;
    return p;
  };
  unsigned short* h = (unsigned short*)alloc((size_t)N * DD * 2);  // 25.6 MB bf16
  float* dinv     = (float*)alloc((size_t)N * 4);
  int*   cnts     = (int*)alloc(((size_t)2 * N + 2 * NF) * 4);  // one zeroed block
  int*   cnt_src  = cnts;
  int*   cnt_tgt  = cnts + N;
  int*   cnt_a2f  = cnts + 2 * N;
  int*   cnt_fe   = cnts + 2 * N + NF;
  int*   off_tgt  = (int*)alloc((size_t)N * 4);
  int*   rank_tgt = (int*)alloc((size_t)E * 4);
  int*   csr_src  = (int*)alloc((size_t)E * 4);
  int*   off_a2f  = (int*)alloc((size_t)NF * 4);
  int*   rank_a2f = (int*)alloc((size_t)N * 4);
  int*   aids     = (int*)alloc((size_t)N * 4);
  int*   off_fe   = (int*)alloc((size_t)NF * 4);
  int*   rank_fe  = (int*)alloc((size_t)FE * 4);
  int*   csr_fs   = (int*)alloc((size_t)FE * 4);
  int*   bsums    = (int*)alloc(1024 * 4);
  float* ff       = (float*)alloc((size_t)NF * DD * 4);
  float* fs       = (float*)alloc((size_t)NF * DD * 4);
  float* hid      = (float*)alloc((size_t)NF * 2 * DD * 4);

  hipMemsetAsync(cnts, 0, ((size_t)2 * N + 2 * NF) * 4, stream);

  // counts/ranks (lean, full occupancy)
  int nb_cnt = (E + N + FE + 255) / 256;
  counts_k<<<nb_cnt, 256, 0, stream>>>(
      esrc, etgt, E, a2f, N, ftgt, FE,
      cnt_src, cnt_tgt, cnt_a2f, cnt_fe, rank_tgt, rank_a2f, rank_fe);

  // scans: 1024-thr bsums + 1024-thr frag scans, then final scan + dinv
  int nb1 = (N + 1023) / 1024;
  bsum1024_k<<<nb1 + 2, 1024, 0, stream>>>(cnt_tgt, N, nb1, bsums,
                                           cnt_a2f, off_a2f, cnt_fe, off_fe, NF);
  scanB_k<<<nb1, 256, 0, stream>>>(cnt_tgt, N, bsums, off_tgt, cnt_src, dinv);

  // h' = bf16((x @ W + b) * dinv)
  mfma_h_k<<<(N + 127) / 128, 256, 0, stream>>>(x_atoms, atom_w, atom_b, dinv, h, N);

  // fill (atomic-free)
  fill_k<<<nb_cnt, 256, 0, stream>>>(
      esrc, etgt, E, a2f, N, fsrc, ftgt, FE,
      off_tgt, rank_tgt, off_a2f, rank_a2f, off_fe, rank_fe,
      csr_src, aids, csr_fs);

  // gathers
  edge_gather_k<<<(N + 7) / 8, 256, 0, stream>>>(off_tgt, cnt_tgt, csr_src, h, dinv, out_atoms, N);
  seg_gather_k<<<(NF + 7) / 8, 256, 0, stream>>>(off_a2f, cnt_a2f, aids, out_atoms, ff, NF);
  seg_gather_k<<<(NF + 7) / 8, 256, 0, stream>>>(off_fe, cnt_fe, csr_fs, ff, fs, NF);

  // MLP (f32, two proven dispatches)
  linear_k<128, 256, true, 32><<<(NF + 31) / 32, 256, 0, stream>>>(fs, frag_w1, frag_b1, hid, NF);
  linear_k<256, 128, false, 16><<<(NF + 31) / 32, 256, 0, stream>>>(hid, frag_w2, frag_b2, out_frags, NF);
}

// Round 10
// 380.213 us; speedup vs baseline: 1.1238x; 1.0297x over previous
//
#include <hip/hip_runtime.h>

constexpr int DD = 128;

typedef __attribute__((ext_vector_type(8))) short short8_t;   // 8 bf16 = 4 VGPR
typedef __attribute__((ext_vector_type(4))) float f32x4;

__device__ __forceinline__ float bf2f(unsigned short u) {
  union { unsigned int i; float f; } c;
  c.i = ((unsigned int)u) << 16;
  return c.f;
}
__device__ __forceinline__ unsigned short f2bf(float f) {
  union { float f; unsigned int i; } c;
  c.f = f;
  unsigned int x = c.i;
  x += 0x7fff + ((x >> 16) & 1);  // RNE
  return (unsigned short)(x >> 16);
}

// ================= counts (lean: no LDS, low VGPR, full occupancy) =================
__global__ void __launch_bounds__(256) counts_k(
    const int* __restrict__ esrc, const int* __restrict__ etgt, int E,
    const int* __restrict__ a2f, int N, const int* __restrict__ ftgt, int FE,
    int* __restrict__ cnt_src, int* __restrict__ cnt_tgt,
    int* __restrict__ cnt_a2f, int* __restrict__ cnt_fe,
    int* __restrict__ rank_tgt, int* __restrict__ rank_a2f, int* __restrict__ rank_fe) {
  int i = blockIdx.x * 256 + threadIdx.x;
  if (i < E) {
    atomicAdd(&cnt_src[esrc[i]], 1);
    rank_tgt[i] = atomicAdd(&cnt_tgt[etgt[i]], 1);
  } else if (i < E + N) {
    int j = i - E;
    rank_a2f[j] = atomicAdd(&cnt_a2f[a2f[j]], 1);
  } else if (i < E + N + FE) {
    int e = i - E - N;
    rank_fe[e] = atomicAdd(&cnt_fe[ftgt[e]], 1);
  }
}

// ===== bsum1024: blocks [0,nb): 1024-thr tree-reduce of cnt_tgt chunk -> bsums;
//       blocks nb, nb+1: 1024-thr exclusive scans of the two 10k frag count arrays =====
__global__ void __launch_bounds__(1024) bsum1024_k(
    const int* __restrict__ cnt_tgt, int n, int nb, int* __restrict__ bsums,
    const int* __restrict__ cnt_a2f, int* __restrict__ off_a2f,
    const int* __restrict__ cnt_fe, int* __restrict__ off_fe, int nf) {
  __shared__ int s[1024];
  int t = threadIdx.x;
  int bid = blockIdx.x;
  if (bid < nb) {
    int g = bid * 1024 + t;
    s[t] = (g < n) ? cnt_tgt[g] : 0;
    __syncthreads();
    for (int d = 512; d > 0; d >>= 1) {
      if (t < d) s[t] += s[t + d];
      __syncthreads();
    }
    if (t == 0) bsums[bid] = s[0];
  } else {
    const int* in = (bid == nb) ? cnt_a2f : cnt_fe;
    int* off = (bid == nb) ? off_a2f : off_fe;
    int carry = 0;
    for (int base = 0; base < nf; base += 1024) {
      int v = (base + t < nf) ? in[base + t] : 0;
      __syncthreads();
      s[t] = v;
      __syncthreads();
      for (int d = 1; d < 1024; d <<= 1) {
        int u = (t >= d) ? s[t - d] : 0;
        __syncthreads();
        s[t] += u;
        __syncthreads();
      }
      int tot = s[1023];
      if (base + t < nf) off[base + t] = s[t] - v + carry;
      carry += tot;
    }
  }
}

// ===== scanB: exclusive scan cnt_tgt -> off_tgt (prefix from bsums inline) + dinv =====
__global__ void __launch_bounds__(256) scanB_k(
    const int* __restrict__ in, int n, const int* __restrict__ bsums,
    int* __restrict__ off, const int* __restrict__ cnt_src,
    float* __restrict__ dinv) {
  __shared__ int s[256];
  int t = threadIdx.x;
  int bid = blockIdx.x;
  s[t] = (t < bid) ? bsums[t] : 0;  // nb <= 256
  __syncthreads();
  for (int d = 128; d > 0; d >>= 1) {
    if (t < d) s[t] += s[t + d];
    __syncthreads();
  }
  int prefix = s[0];
  __syncthreads();

  int base = bid * 1024 + t * 4;
  int a0 = (base + 0 < n) ? in[base + 0] : 0;
  int a1 = (base + 1 < n) ? in[base + 1] : 0;
  int a2 = (base + 2 < n) ? in[base + 2] : 0;
  int a3 = (base + 3 < n) ? in[base + 3] : 0;
  int tot = a0 + a1 + a2 + a3;
  s[t] = tot;
  __syncthreads();
  for (int d = 1; d < 256; d <<= 1) {
    int u = (t >= d) ? s[t - d] : 0;
    __syncthreads();
    s[t] += u;
    __syncthreads();
  }
  int pre = s[t] - tot + prefix;
  int e0 = pre, e1 = pre + a0, e2 = e1 + a1, e3 = e2 + a2;
  if (base + 0 < n) { off[base + 0] = e0; dinv[base + 0] = rsqrtf((float)(cnt_src[base + 0] + 1)); }
  if (base + 1 < n) { off[base + 1] = e1; dinv[base + 1] = rsqrtf((float)(cnt_src[base + 1] + 1)); }
  if (base + 2 < n) { off[base + 2] = e2; dinv[base + 2] = rsqrtf((float)(cnt_src[base + 2] + 1)); }
  if (base + 3 < n) { off[base + 3] = e3; dinv[base + 3] = rsqrtf((float)(cnt_src[base + 3] + 1)); }
}

// ===== merged: MFMA GEMM h'=bf16((x@W+b)*dinv) [blocks 0..nbg) ]
//       + atomic-free CSR fill [blocks nbg..) — both depend only on scanB =====
__global__ void __launch_bounds__(256) gemm_fill_k(
    const float* __restrict__ x, const float* __restrict__ W,
    const float* __restrict__ bias, const float* __restrict__ dinv,
    unsigned short* __restrict__ hout, int nbg,
    const int* __restrict__ esrc, const int* __restrict__ etgt, int E,
    const int* __restrict__ a2f, int N,
    const int* __restrict__ fsrc, const int* __restrict__ ftgt, int FE,
    const int* __restrict__ off_tgt, const int* __restrict__ rank_tgt,
    const int* __restrict__ off_a2f, const int* __restrict__ rank_a2f,
    const int* __restrict__ off_fe, const int* __restrict__ rank_fe,
    int* __restrict__ csr_src, int* __restrict__ aids, int* __restrict__ csr_fs) {
  __shared__ unsigned int wt[8192];  // GEMM path only (32 KB)

  if ((int)blockIdx.x >= nbg) {
    // -------- fill path --------
    int i = ((int)blockIdx.x - nbg) * 256 + threadIdx.x;
    if (i < E) {
      csr_src[off_tgt[etgt[i]] + rank_tgt[i]] = esrc[i];
    } else if (i < E + N) {
      int j = i - E;
      aids[off_a2f[a2f[j]] + rank_a2f[j]] = j;
    } else if (i < E + N + FE) {
      int e = i - E - N;
      csr_fs[off_fe[ftgt[e]] + rank_fe[e]] = fsrc[e];
    }
    return;
  }

  // -------- GEMM path --------
  const int tid = threadIdx.x;
  const int rbase = blockIdx.x * 128;

  {  // stage Wt[c][k] = bf16(W[k][c]), dword-packed (k even|odd), swizzled
    int c = tid & 127;
    int half = tid >> 7;
#pragma unroll 4
    for (int j = 0; j < 32; j++) {
      int p = j * 2 + half;  // dword index = k/2
      int k = p * 2;
      float w0 = W[k * 128 + c];
      float w1 = W[(k + 1) * 128 + c];
      unsigned int packed = (unsigned int)f2bf(w0) | ((unsigned int)f2bf(w1) << 16);
      wt[(64 * c + p) ^ ((c & 7) << 2)] = packed;
    }
  }

  const int wave = tid >> 6;
  const int lane = tid & 63;
  const int l15 = lane & 15;
  const int kg = lane >> 4;

  float bcol[8];
#pragma unroll
  for (int ct = 0; ct < 8; ct++) bcol[ct] = bias[ct * 16 + l15];
  float dv[8];
#pragma unroll
  for (int rt = 0; rt < 2; rt++)
#pragma unroll
    for (int i = 0; i < 4; i++) {
      int gr = rbase + wave * 32 + rt * 16 + kg * 4 + i;
      dv[rt * 4 + i] = (gr < N) ? dinv[gr] : 0.f;
    }

  __syncthreads();

  f32x4 acc[2][8];
#pragma unroll
  for (int rt = 0; rt < 2; rt++)
#pragma unroll
    for (int ct = 0; ct < 8; ct++) acc[rt][ct] = (f32x4)(0.f);

#pragma unroll
  for (int ks = 0; ks < 4; ks++) {
    int kcol = ks * 32 + kg * 8;
    short8_t a[2];
#pragma unroll
    for (int rt = 0; rt < 2; rt++) {
      int row = rbase + wave * 32 + rt * 16 + l15;
      if (row < N) {
        const float4* xr = reinterpret_cast<const float4*>(x + (size_t)row * 128 + kcol);
        float4 v0 = xr[0], v1 = xr[1];
        a[rt][0] = (short)f2bf(v0.x); a[rt][1] = (short)f2bf(v0.y);
        a[rt][2] = (short)f2bf(v0.z); a[rt][3] = (short)f2bf(v0.w);
        a[rt][4] = (short)f2bf(v1.x); a[rt][5] = (short)f2bf(v1.y);
        a[rt][6] = (short)f2bf(v1.z); a[rt][7] = (short)f2bf(v1.w);
      } else {
#pragma unroll
        for (int e = 0; e < 8; e++) a[rt][e] = 0;
      }
    }
#pragma unroll
    for (int ct = 0; ct < 8; ct++) {
      int col = ct * 16 + l15;
      int dw0 = (64 * col + ks * 16 + kg * 4) ^ ((col & 7) << 2);
      short8_t b = *reinterpret_cast<const short8_t*>(&wt[dw0]);
      acc[0][ct] = __builtin_amdgcn_mfma_f32_16x16x32_bf16(a[0], b, acc[0][ct], 0, 0, 0);
      acc[1][ct] = __builtin_amdgcn_mfma_f32_16x16x32_bf16(a[1], b, acc[1][ct], 0, 0, 0);
    }
  }

#pragma unroll
  for (int rt = 0; rt < 2; rt++)
#pragma unroll
    for (int ct = 0; ct < 8; ct++)
#pragma unroll
      for (int i = 0; i < 4; i++) {
        int gr = rbase + wave * 32 + rt * 16 + kg * 4 + i;
        if (gr < N)
          hout[(size_t)gr * 128 + ct * 16 + l15] =
              f2bf((acc[rt][ct][i] + bcol[ct]) * dv[rt * 4 + i]);
      }
}

// ================= Linear f32 (frag MLP, small) =================
template<int IC, int OC, bool RELU, int RPT>
__global__ void __launch_bounds__(256) linear_k(
    const float* __restrict__ in, const float* __restrict__ W,
    const float* __restrict__ bias, float* __restrict__ out, int nrows) {
  constexpr int GROUPS = 256 / OC;
  constexpr int RBLK = RPT * GROUPS;
  __shared__ float xs[RBLK * IC];
  const int tid = threadIdx.x;
  const int c = tid % OC;
  const int g = tid / OC;
  const int rbase = blockIdx.x * RBLK;

  constexpr int NV = RBLK * IC / 4;
  const float4* in4 = reinterpret_cast<const float4*>(in);
  for (int idx = tid; idx < NV; idx += 256) {
    int r = idx / (IC / 4);
    int kk = idx % (IC / 4);
    int gr = rbase + r;
    float4 v = make_float4(0.f, 0.f, 0.f, 0.f);
    if (gr < nrows) v = in4[(size_t)gr * (IC / 4) + kk];
    reinterpret_cast<float4*>(xs)[idx] = v;
  }
  __syncthreads();

  float acc[RPT];
  float b = bias[c];
#pragma unroll
  for (int m = 0; m < RPT; m++) acc[m] = b;

#pragma unroll 4
  for (int k = 0; k < IC; k++) {
    float w = W[k * OC + c];
#pragma unroll
    for (int m = 0; m < RPT; m++)
      acc[m] += xs[(g + m * GROUPS) * IC + k] * w;
  }

#pragma unroll
  for (int m = 0; m < RPT; m++) {
    int gr = rbase + g + m * GROUPS;
    if (gr < nrows) {
      float v = acc[m];
      if (RELU) v = fmaxf(v, 0.f);
      out[(size_t)gr * OC + c] = v;
    }
  }
}

// ===== edge gather (R4-proven): out[t] = dinv[t]*(h'[t] + sum_s h'[s]); h' = dinv*h bf16 =====
__global__ void __launch_bounds__(256) edge_gather_k(
    const int* __restrict__ off, const int* __restrict__ cnt,
    const int* __restrict__ csr_src, const unsigned short* __restrict__ h,
    const float* __restrict__ dinv, float* __restrict__ out, int n) {
  int tn = blockIdx.x * 8 + (threadIdx.x >> 5);
  if (tn >= n) return;
  int lane = threadIdx.x & 31;
  const ushort4* h4 = reinterpret_cast<const ushort4*>(h);
  ushort4 hv = h4[(size_t)tn * 32 + lane];
  float ax = bf2f(hv.x), ay = bf2f(hv.y), az = bf2f(hv.z), aw = bf2f(hv.w);
  int s0 = off[tn], c = cnt[tn];
  int i = 0;
  for (; i + 4 <= c; i += 4) {
    int s1 = csr_src[s0 + i + 0];
    int s2 = csr_src[s0 + i + 1];
    int s3 = csr_src[s0 + i + 2];
    int s4 = csr_src[s0 + i + 3];
    ushort4 v1 = h4[(size_t)s1 * 32 + lane];
    ushort4 v2 = h4[(size_t)s2 * 32 + lane];
    ushort4 v3 = h4[(size_t)s3 * 32 + lane];
    ushort4 v4 = h4[(size_t)s4 * 32 + lane];
    ax += (bf2f(v1.x) + bf2f(v2.x)) + (bf2f(v3.x) + bf2f(v4.x));
    ay += (bf2f(v1.y) + bf2f(v2.y)) + (bf2f(v3.y) + bf2f(v4.y));
    az += (bf2f(v1.z) + bf2f(v2.z)) + (bf2f(v3.z) + bf2f(v4.z));
    aw += (bf2f(v1.w) + bf2f(v2.w)) + (bf2f(v3.w) + bf2f(v4.w));
  }
  for (; i < c; i++) {
    int s1 = csr_src[s0 + i];
    ushort4 v1 = h4[(size_t)s1 * 32 + lane];
    ax += bf2f(v1.x); ay += bf2f(v1.y); az += bf2f(v1.z); aw += bf2f(v1.w);
  }
  float dt = dinv[tn];
  reinterpret_cast<float4*>(out)[(size_t)tn * 32 + lane] =
      make_float4(ax * dt, ay * dt, az * dt, aw * dt);
}

// dst[f] = sum_{a in group f} src_rows[a]  (f32 rows)
__global__ void __launch_bounds__(256) seg_gather_k(
    const int* __restrict__ off, const int* __restrict__ cnt,
    const int* __restrict__ ids, const float* __restrict__ src_rows,
    float* __restrict__ dst, int n) {
  int f = blockIdx.x * 8 + (threadIdx.x >> 5);
  if (f >= n) return;
  int lane = threadIdx.x & 31;
  const float4* s4 = reinterpret_cast<const float4*>(src_rows);
  float ax = 0.f, ay = 0.f, az = 0.f, aw = 0.f;
  int s0 = off[f], c = cnt[f];
  int i = 0;
  for (; i + 2 <= c; i += 2) {
    int a1 = ids[s0 + i], a2 = ids[s0 + i + 1];
    float4 v1 = s4[(size_t)a1 * 32 + lane];
    float4 v2 = s4[(size_t)a2 * 32 + lane];
    ax += v1.x + v2.x; ay += v1.y + v2.y; az += v1.z + v2.z; aw += v1.w + v2.w;
  }
  if (i < c) {
    int a1 = ids[s0 + i];
    float4 v1 = s4[(size_t)a1 * 32 + lane];
    ax += v1.x; ay += v1.y; az += v1.z; aw += v1.w;
  }
  reinterpret_cast<float4*>(dst)[(size_t)f * 32 + lane] = make_float4(ax, ay, az, aw);
}

// ================= launch =================
extern "C" void kernel_launch(void* const* d_in, const int* in_sizes, int n_in,
                              void* d_out, int out_size, void* d_ws, size_t ws_size,
                              hipStream_t stream) {
  const float* x_atoms    = (const float*)d_in[0];
  const int*   edge_index = (const int*)d_in[1];
  // d_in[2] edge_attr: dead in reference — never read.
  const int*   frag_index = (const int*)d_in[3];
  // d_in[4] x_frags: values unused.
  const int*   a2f     = (const int*)d_in[5];
  const float* atom_w  = (const float*)d_in[6];
  const float* atom_b  = (const float*)d_in[7];
  // d_in[8..9] edge_w/edge_b: unused.
  const float* frag_w1 = (const float*)d_in[10];
  const float* frag_b1 = (const float*)d_in[11];
  const float* frag_w2 = (const float*)d_in[12];
  const float* frag_b2 = (const float*)d_in[13];

  const int N  = in_sizes[0] / DD;   // 100000
  const int E  = in_sizes[1] / 2;    // 1600000
  const int FE = in_sizes[3] / 2;    // 80000
  const int NF = in_sizes[4] / DD;   // 10000

  const int* esrc = edge_index;
  const int* etgt = edge_index + E;
  const int* fsrc = frag_index;
  const int* ftgt = frag_index + FE;

  float* out_atoms = (float*)d_out;
  float* out_frags = out_atoms + (size_t)N * DD;

  char* ws = (char*)d_ws;
  size_t off_b = 0;
  auto alloc = [&](size_t bytes) {
    void* p = ws + off_b;
    off_b += (bytes + 255) & ~(size_t)255;
    return p;
  };
  unsigned short* h = (unsigned short*)alloc((size_t)N * DD * 2);  // 25.6 MB bf16
  float* dinv     = (float*)alloc((size_t)N * 4);
  int*   cnts     = (int*)alloc(((size_t)2 * N + 2 * NF) * 4);  // one zeroed block
  int*   cnt_src  = cnts;
  int*   cnt_tgt  = cnts + N;
  int*   cnt_a2f  = cnts + 2 * N;
  int*   cnt_fe   = cnts + 2 * N + NF;
  int*   off_tgt  = (int*)alloc((size_t)N * 4);
  int*   rank_tgt = (int*)alloc((size_t)E * 4);
  int*   csr_src  = (int*)alloc((size_t)E * 4);
  int*   off_a2f  = (int*)alloc((size_t)NF * 4);
  int*   rank_a2f = (int*)alloc((size_t)N * 4);
  int*   aids     = (int*)alloc((size_t)N * 4);
  int*   off_fe   = (int*)alloc((size_t)NF * 4);
  int*   rank_fe  = (int*)alloc((size_t)FE * 4);
  int*   csr_fs   = (int*)alloc((size_t)FE * 4);
  int*   bsums    = (int*)alloc(1024 * 4);
  float* ff       = (float*)alloc((size_t)NF * DD * 4);
  float* fs       = (float*)alloc((size_t)NF * DD * 4);
  float* hid      = (float*)alloc((size_t)NF * 2 * DD * 4);

  hipMemsetAsync(cnts, 0, ((size_t)2 * N + 2 * NF) * 4, stream);

  // counts/ranks (lean, full occupancy)
  int nb_cnt = (E + N + FE + 255) / 256;
  counts_k<<<nb_cnt, 256, 0, stream>>>(
      esrc, etgt, E, a2f, N, ftgt, FE,
      cnt_src, cnt_tgt, cnt_a2f, cnt_fe, rank_tgt, rank_a2f, rank_fe);

  // scans: 1024-thr bsums + 1024-thr frag scans, then final scan + dinv
  int nb1 = (N + 1023) / 1024;
  bsum1024_k<<<nb1 + 2, 1024, 0, stream>>>(cnt_tgt, N, nb1, bsums,
                                           cnt_a2f, off_a2f, cnt_fe, off_fe, NF);
  scanB_k<<<nb1, 256, 0, stream>>>(cnt_tgt, N, bsums, off_tgt, cnt_src, dinv);

  // merged GEMM (h') + fill — both depend only on scanB; GEMM blocks first
  int nb_gemm = (N + 127) / 128;
  gemm_fill_k<<<nb_gemm + nb_cnt, 256, 0, stream>>>(
      x_atoms, atom_w, atom_b, dinv, h, nb_gemm,
      esrc, etgt, E, a2f, N, fsrc, ftgt, FE,
      off_tgt, rank_tgt, off_a2f, rank_a2f, off_fe, rank_fe,
      csr_src, aids, csr_fs);

  // gathers
  edge_gather_k<<<(N + 7) / 8, 256, 0, stream>>>(off_tgt, cnt_tgt, csr_src, h, dinv, out_atoms, N);
  seg_gather_k<<<(NF + 7) / 8, 256, 0, stream>>>(off_a2f, cnt_a2f, aids, out_atoms, ff, NF);
  seg_gather_k<<<(NF + 7) / 8, 256, 0, stream>>>(off_fe, cnt_fe, csr_fs, ff, fs, NF);

  // MLP (f32, two proven dispatches)
  linear_k<128, 256, true, 32><<<(NF + 31) / 32, 256, 0, stream>>>(fs, frag_w1, frag_b1, hid, NF);
  linear_k<256, 128, false, 16><<<(NF + 31) / 32, 256, 0, stream>>>(hid, frag_w2, frag_b2, out_frags, NF);
}

// Round 11
// 379.763 us; speedup vs baseline: 1.1251x; 1.0012x over previous
//
#include <hip/hip_runtime.h>

constexpr int DD = 128;

typedef __attribute__((ext_vector_type(8))) short short8_t;            // 8 bf16 = 4 VGPR
typedef __attribute__((ext_vector_type(8))) unsigned short ushort8_t;  // 16 B
typedef __attribute__((ext_vector_type(4))) float f32x4;

__device__ __forceinline__ float bf2f(unsigned short u) {
  union { unsigned int i; float f; } c;
  c.i = ((unsigned int)u) << 16;
  return c.f;
}
__device__ __forceinline__ unsigned short f2bf(float f) {
  union { float f; unsigned int i; } c;
  c.f = f;
  unsigned int x = c.i;
  x += 0x7fff + ((x >> 16) & 1);  // RNE
  return (unsigned short)(x >> 16);
}

// ===== merged dispatch 1: MFMA GEMM h=bf16(x@W+b) [blocks 0..nbg) — NO deps]
//       + counts/ranks [blocks nbg..) — the only atomic pass =====
__global__ void __launch_bounds__(256) counts_gemm_k(
    const float* __restrict__ x, const float* __restrict__ W,
    const float* __restrict__ bias, unsigned short* __restrict__ hout, int nbg,
    const int* __restrict__ esrc, const int* __restrict__ etgt, int E,
    const int* __restrict__ a2f, int N, const int* __restrict__ ftgt, int FE,
    int* __restrict__ cnt_src, int* __restrict__ cnt_tgt,
    int* __restrict__ cnt_a2f, int* __restrict__ cnt_fe,
    int* __restrict__ rank_tgt, int* __restrict__ rank_a2f, int* __restrict__ rank_fe) {
  __shared__ unsigned int wt[8192];  // GEMM path only (32 KB)

  if ((int)blockIdx.x >= nbg) {
    // -------- counts path --------
    int i = ((int)blockIdx.x - nbg) * 256 + threadIdx.x;
    if (i < E) {
      atomicAdd(&cnt_src[esrc[i]], 1);
      rank_tgt[i] = atomicAdd(&cnt_tgt[etgt[i]], 1);
    } else if (i < E + N) {
      int j = i - E;
      rank_a2f[j] = atomicAdd(&cnt_a2f[a2f[j]], 1);
    } else if (i < E + N + FE) {
      int e = i - E - N;
      rank_fe[e] = atomicAdd(&cnt_fe[ftgt[e]], 1);
    }
    return;
  }

  // -------- GEMM path (unscaled h) --------
  const int tid = threadIdx.x;
  const int rbase = blockIdx.x * 128;

  {  // stage Wt[c][k] = bf16(W[k][c]), dword-packed (k even|odd), swizzled
    int c = tid & 127;
    int half = tid >> 7;
#pragma unroll 4
    for (int j = 0; j < 32; j++) {
      int p = j * 2 + half;  // dword index = k/2
      int k = p * 2;
      float w0 = W[k * 128 + c];
      float w1 = W[(k + 1) * 128 + c];
      unsigned int packed = (unsigned int)f2bf(w0) | ((unsigned int)f2bf(w1) << 16);
      wt[(64 * c + p) ^ ((c & 7) << 2)] = packed;
    }
  }

  const int wave = tid >> 6;
  const int lane = tid & 63;
  const int l15 = lane & 15;
  const int kg = lane >> 4;

  float bcol[8];
#pragma unroll
  for (int ct = 0; ct < 8; ct++) bcol[ct] = bias[ct * 16 + l15];

  __syncthreads();

  f32x4 acc[2][8];
#pragma unroll
  for (int rt = 0; rt < 2; rt++)
#pragma unroll
    for (int ct = 0; ct < 8; ct++) acc[rt][ct] = (f32x4)(0.f);

#pragma unroll
  for (int ks = 0; ks < 4; ks++) {
    int kcol = ks * 32 + kg * 8;
    short8_t a[2];
#pragma unroll
    for (int rt = 0; rt < 2; rt++) {
      int row = rbase + wave * 32 + rt * 16 + l15;
      if (row < N) {
        const float4* xr = reinterpret_cast<const float4*>(x + (size_t)row * 128 + kcol);
        float4 v0 = xr[0], v1 = xr[1];
        a[rt][0] = (short)f2bf(v0.x); a[rt][1] = (short)f2bf(v0.y);
        a[rt][2] = (short)f2bf(v0.z); a[rt][3] = (short)f2bf(v0.w);
        a[rt][4] = (short)f2bf(v1.x); a[rt][5] = (short)f2bf(v1.y);
        a[rt][6] = (short)f2bf(v1.z); a[rt][7] = (short)f2bf(v1.w);
      } else {
#pragma unroll
        for (int e = 0; e < 8; e++) a[rt][e] = 0;
      }
    }
#pragma unroll
    for (int ct = 0; ct < 8; ct++) {
      int col = ct * 16 + l15;
      int dw0 = (64 * col + ks * 16 + kg * 4) ^ ((col & 7) << 2);
      short8_t b = *reinterpret_cast<const short8_t*>(&wt[dw0]);
      acc[0][ct] = __builtin_amdgcn_mfma_f32_16x16x32_bf16(a[0], b, acc[0][ct], 0, 0, 0);
      acc[1][ct] = __builtin_amdgcn_mfma_f32_16x16x32_bf16(a[1], b, acc[1][ct], 0, 0, 0);
    }
  }

#pragma unroll
  for (int rt = 0; rt < 2; rt++)
#pragma unroll
    for (int ct = 0; ct < 8; ct++)
#pragma unroll
      for (int i = 0; i < 4; i++) {
        int gr = rbase + wave * 32 + rt * 16 + kg * 4 + i;
        if (gr < N)
          hout[(size_t)gr * 128 + ct * 16 + l15] = f2bf(acc[rt][ct][i] + bcol[ct]);
      }
}

// ===== bsum1024: blocks [0,nb): 1024-thr tree-reduce of cnt_tgt chunk -> bsums;
//       blocks nb, nb+1: 1024-thr exclusive scans of the two 10k frag count arrays =====
__global__ void __launch_bounds__(1024) bsum1024_k(
    const int* __restrict__ cnt_tgt, int n, int nb, int* __restrict__ bsums,
    const int* __restrict__ cnt_a2f, int* __restrict__ off_a2f,
    const int* __restrict__ cnt_fe, int* __restrict__ off_fe, int nf) {
  __shared__ int s[1024];
  int t = threadIdx.x;
  int bid = blockIdx.x;
  if (bid < nb) {
    int g = bid * 1024 + t;
    s[t] = (g < n) ? cnt_tgt[g] : 0;
    __syncthreads();
    for (int d = 512; d > 0; d >>= 1) {
      if (t < d) s[t] += s[t + d];
      __syncthreads();
    }
    if (t == 0) bsums[bid] = s[0];
  } else {
    const int* in = (bid == nb) ? cnt_a2f : cnt_fe;
    int* off = (bid == nb) ? off_a2f : off_fe;
    int carry = 0;
    for (int base = 0; base < nf; base += 1024) {
      int v = (base + t < nf) ? in[base + t] : 0;
      __syncthreads();
      s[t] = v;
      __syncthreads();
      for (int d = 1; d < 1024; d <<= 1) {
        int u = (t >= d) ? s[t - d] : 0;
        __syncthreads();
        s[t] += u;
        __syncthreads();
      }
      int tot = s[1023];
      if (base + t < nf) off[base + t] = s[t] - v + carry;
      carry += tot;
    }
  }
}

// ===== scanB: exclusive scan cnt_tgt -> off_tgt (prefix from bsums inline) + dinv =====
__global__ void __launch_bounds__(256) scanB_k(
    const int* __restrict__ in, int n, const int* __restrict__ bsums,
    int* __restrict__ off, const int* __restrict__ cnt_src,
    float* __restrict__ dinv) {
  __shared__ int s[256];
  int t = threadIdx.x;
  int bid = blockIdx.x;
  s[t] = (t < bid) ? bsums[t] : 0;  // nb <= 256
  __syncthreads();
  for (int d = 128; d > 0; d >>= 1) {
    if (t < d) s[t] += s[t + d];
    __syncthreads();
  }
  int prefix = s[0];
  __syncthreads();

  int base = bid * 1024 + t * 4;
  int a0 = (base + 0 < n) ? in[base + 0] : 0;
  int a1 = (base + 1 < n) ? in[base + 1] : 0;
  int a2 = (base + 2 < n) ? in[base + 2] : 0;
  int a3 = (base + 3 < n) ? in[base + 3] : 0;
  int tot = a0 + a1 + a2 + a3;
  s[t] = tot;
  __syncthreads();
  for (int d = 1; d < 256; d <<= 1) {
    int u = (t >= d) ? s[t - d] : 0;
    __syncthreads();
    s[t] += u;
    __syncthreads();
  }
  int pre = s[t] - tot + prefix;
  int e0 = pre, e1 = pre + a0, e2 = e1 + a1, e3 = e2 + a2;
  if (base + 0 < n) { off[base + 0] = e0; dinv[base + 0] = rsqrtf((float)(cnt_src[base + 0] + 1)); }
  if (base + 1 < n) { off[base + 1] = e1; dinv[base + 1] = rsqrtf((float)(cnt_src[base + 1] + 1)); }
  if (base + 2 < n) { off[base + 2] = e2; dinv[base + 2] = rsqrtf((float)(cnt_src[base + 2] + 1)); }
  if (base + 3 < n) { off[base + 3] = e3; dinv[base + 3] = rsqrtf((float)(cnt_src[base + 3] + 1)); }
}

// ===== dispatch 4: fill (atomic-free, blocks [0,nbf)) + in-place h *= dinv (blocks after) =====
__global__ void __launch_bounds__(256) fill_scale_k(
    const int* __restrict__ esrc, const int* __restrict__ etgt, int E,
    const int* __restrict__ a2f, int N,
    const int* __restrict__ fsrc, const int* __restrict__ ftgt, int FE,
    const int* __restrict__ off_tgt, const int* __restrict__ rank_tgt,
    const int* __restrict__ off_a2f, const int* __restrict__ rank_a2f,
    const int* __restrict__ off_fe, const int* __restrict__ rank_fe,
    int* __restrict__ csr_src, int* __restrict__ aids, int* __restrict__ csr_fs,
    unsigned short* __restrict__ h, const float* __restrict__ dinv, int nbf) {
  if ((int)blockIdx.x >= nbf) {
    // scale path: each thread scales 8 consecutive bf16 (one row = 16 threads)
    int idx = ((int)blockIdx.x - nbf) * 256 + threadIdx.x;
    if (idx < N * 16) {
      float d = dinv[idx >> 4];
      ushort8_t v = reinterpret_cast<ushort8_t*>(h)[idx];
#pragma unroll
      for (int e = 0; e < 8; e++) v[e] = f2bf(bf2f(v[e]) * d);
      reinterpret_cast<ushort8_t*>(h)[idx] = v;
    }
    return;
  }
  int i = blockIdx.x * 256 + threadIdx.x;
  if (i < E) {
    csr_src[off_tgt[etgt[i]] + rank_tgt[i]] = esrc[i];
  } else if (i < E + N) {
    int j = i - E;
    aids[off_a2f[a2f[j]] + rank_a2f[j]] = j;
  } else if (i < E + N + FE) {
    int e = i - E - N;
    csr_fs[off_fe[ftgt[e]] + rank_fe[e]] = fsrc[e];
  }
}

// ================= Linear f32 (frag MLP, small) =================
template<int IC, int OC, bool RELU, int RPT>
__global__ void __launch_bounds__(256) linear_k(
    const float* __restrict__ in, const float* __restrict__ W,
    const float* __restrict__ bias, float* __restrict__ out, int nrows) {
  constexpr int GROUPS = 256 / OC;
  constexpr int RBLK = RPT * GROUPS;
  __shared__ float xs[RBLK * IC];
  const int tid = threadIdx.x;
  const int c = tid % OC;
  const int g = tid / OC;
  const int rbase = blockIdx.x * RBLK;

  constexpr int NV = RBLK * IC / 4;
  const float4* in4 = reinterpret_cast<const float4*>(in);
  for (int idx = tid; idx < NV; idx += 256) {
    int r = idx / (IC / 4);
    int kk = idx % (IC / 4);
    int gr = rbase + r;
    float4 v = make_float4(0.f, 0.f, 0.f, 0.f);
    if (gr < nrows) v = in4[(size_t)gr * (IC / 4) + kk];
    reinterpret_cast<float4*>(xs)[idx] = v;
  }
  __syncthreads();

  float acc[RPT];
  float b = bias[c];
#pragma unroll
  for (int m = 0; m < RPT; m++) acc[m] = b;

#pragma unroll 4
  for (int k = 0; k < IC; k++) {
    float w = W[k * OC + c];
#pragma unroll
    for (int m = 0; m < RPT; m++)
      acc[m] += xs[(g + m * GROUPS) * IC + k] * w;
  }

#pragma unroll
  for (int m = 0; m < RPT; m++) {
    int gr = rbase + g + m * GROUPS;
    if (gr < nrows) {
      float v = acc[m];
      if (RELU) v = fmaxf(v, 0.f);
      out[(size_t)gr * OC + c] = v;
    }
  }
}

// ===== edge gather (R4-proven): out[t] = dinv[t]*(h'[t] + sum_s h'[s]); h' = dinv*h bf16 =====
__global__ void __launch_bounds__(256) edge_gather_k(
    const int* __restrict__ off, const int* __restrict__ cnt,
    const int* __restrict__ csr_src, const unsigned short* __restrict__ h,
    const float* __restrict__ dinv, float* __restrict__ out, int n) {
  int tn = blockIdx.x * 8 + (threadIdx.x >> 5);
  if (tn >= n) return;
  int lane = threadIdx.x & 31;
  const ushort4* h4 = reinterpret_cast<const ushort4*>(h);
  ushort4 hv = h4[(size_t)tn * 32 + lane];
  float ax = bf2f(hv.x), ay = bf2f(hv.y), az = bf2f(hv.z), aw = bf2f(hv.w);
  int s0 = off[tn], c = cnt[tn];
  int i = 0;
  for (; i + 4 <= c; i += 4) {
    int s1 = csr_src[s0 + i + 0];
    int s2 = csr_src[s0 + i + 1];
    int s3 = csr_src[s0 + i + 2];
    int s4 = csr_src[s0 + i + 3];
    ushort4 v1 = h4[(size_t)s1 * 32 + lane];
    ushort4 v2 = h4[(size_t)s2 * 32 + lane];
    ushort4 v3 = h4[(size_t)s3 * 32 + lane];
    ushort4 v4 = h4[(size_t)s4 * 32 + lane];
    ax += (bf2f(v1.x) + bf2f(v2.x)) + (bf2f(v3.x) + bf2f(v4.x));
    ay += (bf2f(v1.y) + bf2f(v2.y)) + (bf2f(v3.y) + bf2f(v4.y));
    az += (bf2f(v1.z) + bf2f(v2.z)) + (bf2f(v3.z) + bf2f(v4.z));
    aw += (bf2f(v1.w) + bf2f(v2.w)) + (bf2f(v3.w) + bf2f(v4.w));
  }
  for (; i < c; i++) {
    int s1 = csr_src[s0 + i];
    ushort4 v1 = h4[(size_t)s1 * 32 + lane];
    ax += bf2f(v1.x); ay += bf2f(v1.y); az += bf2f(v1.z); aw += bf2f(v1.w);
  }
  float dt = dinv[tn];
  reinterpret_cast<float4*>(out)[(size_t)tn * 32 + lane] =
      make_float4(ax * dt, ay * dt, az * dt, aw * dt);
}

// dst[f] = sum_{a in group f} src_rows[a]  (f32 rows)
__global__ void __launch_bounds__(256) seg_gather_k(
    const int* __restrict__ off, const int* __restrict__ cnt,
    const int* __restrict__ ids, const float* __restrict__ src_rows,
    float* __restrict__ dst, int n) {
  int f = blockIdx.x * 8 + (threadIdx.x >> 5);
  if (f >= n) return;
  int lane = threadIdx.x & 31;
  const float4* s4 = reinterpret_cast<const float4*>(src_rows);
  float ax = 0.f, ay = 0.f, az = 0.f, aw = 0.f;
  int s0 = off[f], c = cnt[f];
  int i = 0;
  for (; i + 2 <= c; i += 2) {
    int a1 = ids[s0 + i], a2 = ids[s0 + i + 1];
    float4 v1 = s4[(size_t)a1 * 32 + lane];
    float4 v2 = s4[(size_t)a2 * 32 + lane];
    ax += v1.x + v2.x; ay += v1.y + v2.y; az += v1.z + v2.z; aw += v1.w + v2.w;
  }
  if (i < c) {
    int a1 = ids[s0 + i];
    float4 v1 = s4[(size_t)a1 * 32 + lane];
    ax += v1.x; ay += v1.y; az += v1.z; aw += v1.w;
  }
  reinterpret_cast<float4*>(dst)[(size_t)f * 32 + lane] = make_float4(ax, ay, az, aw);
}

// ================= launch =================
extern "C" void kernel_launch(void* const* d_in, const int* in_sizes, int n_in,
                              void* d_out, int out_size, void* d_ws, size_t ws_size,
                              hipStream_t stream) {
  const float* x_atoms    = (const float*)d_in[0];
  const int*   edge_index = (const int*)d_in[1];
  // d_in[2] edge_attr: dead in reference — never read.
  const int*   frag_index = (const int*)d_in[3];
  // d_in[4] x_frags: values unused.
  const int*   a2f     = (const int*)d_in[5];
  const float* atom_w  = (const float*)d_in[6];
  const float* atom_b  = (const float*)d_in[7];
  // d_in[8..9] edge_w/edge_b: unused.
  const float* frag_w1 = (const float*)d_in[10];
  const float* frag_b1 = (const float*)d_in[11];
  const float* frag_w2 = (const float*)d_in[12];
  const float* frag_b2 = (const float*)d_in[13];

  const int N  = in_sizes[0] / DD;   // 100000
  const int E  = in_sizes[1] / 2;    // 1600000
  const int FE = in_sizes[3] / 2;    // 80000
  const int NF = in_sizes[4] / DD;   // 10000

  const int* esrc = edge_index;
  const int* etgt = edge_index + E;
  const int* fsrc = frag_index;
  const int* ftgt = frag_index + FE;

  float* out_atoms = (float*)d_out;
  float* out_frags = out_atoms + (size_t)N * DD;

  char* ws = (char*)d_ws;
  size_t off_b = 0;
  auto alloc = [&](size_t bytes) {
    void* p = ws + off_b;
    off_b += (bytes + 255) & ~(size_t)255;
    return p;
  };
  unsigned short* h = (unsigned short*)alloc((size_t)N * DD * 2);  // 25.6 MB bf16
  float* dinv     = (float*)alloc((size_t)N * 4);
  int*   cnts     = (int*)alloc(((size_t)2 * N + 2 * NF) * 4);  // one zeroed block
  int*   cnt_src  = cnts;
  int*   cnt_tgt  = cnts + N;
  int*   cnt_a2f  = cnts + 2 * N;
  int*   cnt_fe   = cnts + 2 * N + NF;
  int*   off_tgt  = (int*)alloc((size_t)N * 4);
  int*   rank_tgt = (int*)alloc((size_t)E * 4);
  int*   csr_src  = (int*)alloc((size_t)E * 4);
  int*   off_a2f  = (int*)alloc((size_t)NF * 4);
  int*   rank_a2f = (int*)alloc((size_t)N * 4);
  int*   aids     = (int*)alloc((size_t)N * 4);
  int*   off_fe   = (int*)alloc((size_t)NF * 4);
  int*   rank_fe  = (int*)alloc((size_t)FE * 4);
  int*   csr_fs   = (int*)alloc((size_t)FE * 4);
  int*   bsums    = (int*)alloc(1024 * 4);
  float* ff       = (float*)alloc((size_t)NF * DD * 4);
  float* fs       = (float*)alloc((size_t)NF * DD * 4);
  float* hid      = (float*)alloc((size_t)NF * 2 * DD * 4);

  hipMemsetAsync(cnts, 0, ((size_t)2 * N + 2 * NF) * 4, stream);

  // dispatch 1: GEMM (no deps) ∥ counts/ranks — GEMM blocks first
  int nb_gemm = (N + 127) / 128;
  int nb_cnt = (E + N + FE + 255) / 256;
  counts_gemm_k<<<nb_gemm + nb_cnt, 256, 0, stream>>>(
      x_atoms, atom_w, atom_b, h, nb_gemm,
      esrc, etgt, E, a2f, N, ftgt, FE,
      cnt_src, cnt_tgt, cnt_a2f, cnt_fe, rank_tgt, rank_a2f, rank_fe);

  // scans: 1024-thr bsums + frag scans, then final scan + dinv
  int nb1 = (N + 1023) / 1024;
  bsum1024_k<<<nb1 + 2, 1024, 0, stream>>>(cnt_tgt, N, nb1, bsums,
                                           cnt_a2f, off_a2f, cnt_fe, off_fe, NF);
  scanB_k<<<nb1, 256, 0, stream>>>(cnt_tgt, N, bsums, off_tgt, cnt_src, dinv);

  // dispatch 4: fill (atomic-free) ∥ h *= dinv scale
  int nb_scale = (N * 16 + 255) / 256;
  fill_scale_k<<<nb_cnt + nb_scale, 256, 0, stream>>>(
      esrc, etgt, E, a2f, N, fsrc, ftgt, FE,
      off_tgt, rank_tgt, off_a2f, rank_a2f, off_fe, rank_fe,
      csr_src, aids, csr_fs, h, dinv, nb_cnt);

  // gathers
  edge_gather_k<<<(N + 7) / 8, 256, 0, stream>>>(off_tgt, cnt_tgt, csr_src, h, dinv, out_atoms, N);
  seg_gather_k<<<(NF + 7) / 8, 256, 0, stream>>>(off_a2f, cnt_a2f, aids, out_atoms, ff, NF);
  seg_gather_k<<<(NF + 7) / 8, 256, 0, stream>>>(off_fe, cnt_fe, csr_fs, ff, fs, NF);

  // MLP (f32, two proven dispatches)
  linear_k<128, 256, true, 32><<<(NF + 31) / 32, 256, 0, stream>>>(fs, frag_w1, frag_b1, hid, NF);
  linear_k<256, 128, false, 16><<<(NF + 31) / 32, 256, 0, stream>>>(hid, frag_w2, frag_b2, out_frags, NF);
}